// Round 1
// baseline (1388.471 us; speedup 1.0000x reference)
//
#include <hip/hip_runtime.h>
#include <stdint.h>

#define BB 4
#define CC 128
#define DD 64
#define NN 2048
#define MM 2048
#define HH 256
#define KK 16
#define NSAMP 131072   // B*N*K
#define NPTS  8192     // B*N

// ---------------------------------------------------------------------------
// prep: transpose weights for coalesced reads + zero the stats accumulators
// ---------------------------------------------------------------------------
__global__ __launch_bounds__(256) void k_prep(
    const float* __restrict__ Wq, const float* __restrict__ Wk, const float* __restrict__ Wv,
    const float* __restrict__ Wp2, const float* __restrict__ Wa2,
    float* __restrict__ Wqt, float* __restrict__ Wkt, float* __restrict__ Wvt,
    float* __restrict__ Wp2t, float* __restrict__ Wa2t, float* __restrict__ statz) {
  int gid = blockIdx.x * 256 + threadIdx.x;   // grid 64*256 = 16384
  if (gid < 8192)  { int c = gid >> 6, d = gid & 63;
    Wqt[gid] = Wq[d*CC + c]; Wkt[gid] = Wk[d*CC + c]; Wvt[gid] = Wv[d*CC + c]; }
  if (gid < 4096)  { int i = gid >> 6, d = gid & 63; Wp2t[gid] = Wp2[d*DD + i]; }
  if (gid < 16384) { int j = gid >> 6, d = gid & 63; Wa2t[gid] = Wa2[d*HH + j]; }
  if (gid < 4176)  statz[gid] = 0.f;          // 16 pos-stats + 64 ySum + 4096 Gram
}

// ---------------------------------------------------------------------------
// q/k/v 1x1 conv: out[(b*N+n)*64+d] = W[d,:]·x[b,:,n] + bias[d]  (n-major out)
// ---------------------------------------------------------------------------
__global__ __launch_bounds__(256) void k_qkv(
    const float* __restrict__ fq, const float* __restrict__ fs,
    const float* __restrict__ Wqt, const float* __restrict__ Wkt, const float* __restrict__ Wvt,
    const float* __restrict__ bq, const float* __restrict__ bk, const float* __restrict__ bv,
    float* __restrict__ qT, float* __restrict__ kT, float* __restrict__ vT) {
  int bid = blockIdx.x;              // 3 * 4 * 256 = 3072
  int mat = bid >> 10;
  int rem = bid & 1023;
  int b  = rem >> 8;
  int n0 = (rem & 255) * 8;
  int t = threadIdx.x, d = t & 63, pc = t >> 6;
  const float* W   = mat == 0 ? Wqt : (mat == 1 ? Wkt : Wvt);
  const float* src = mat == 0 ? fq  : fs;
  const float* bia = mat == 0 ? bq  : (mat == 1 ? bk : bv);
  float* dst = mat == 0 ? qT : (mat == 1 ? kT : vT);
  int n_a = n0 + pc, n_b = n0 + 4 + pc;
  const float* sa = src + b * CC * NN;
  float acc0 = bia[d], acc1 = acc0;
  #pragma unroll 8
  for (int c = 0; c < CC; ++c) {
    float w = W[c * 64 + d];
    acc0 = fmaf(w, sa[c * NN + n_a], acc0);
    acc1 = fmaf(w, sa[c * NN + n_b], acc1);
  }
  dst[(b * NN + n_a) * 64 + d] = acc0;
  dst[(b * NN + n_b) * 64 + d] = acc1;
}

// ---------------------------------------------------------------------------
// KNN: one wave per query. Per-lane sorted top-16 over 32 candidates,
// then 16-round wave merge via shuffle-min on (d2bits<<32|idx).
// ---------------------------------------------------------------------------
__global__ __launch_bounds__(256) void k_knn(
    const float* __restrict__ pq, const float* __restrict__ ps, int* __restrict__ idxb) {
  __shared__ unsigned long long cand[4][64 * 16];
  int t = threadIdx.x, w = t >> 6, lane = t & 63;
  int qi = blockIdx.x * 4 + w;       // 0..8191
  int b = qi >> 11, n = qi & 2047;
  const float* pqb = pq + b * 3 * NN;
  const float* psb = ps + b * 3 * MM;
  float qx = pqb[n], qy = pqb[NN + n], qz = pqb[2 * NN + n];
  float qq = qx * qx + qy * qy + qz * qz;
  unsigned long long list[16];
  #pragma unroll
  for (int i = 0; i < 16; ++i) list[i] = ~0ULL;
  for (int m = lane; m < MM; m += 64) {
    float sx = psb[m], sy = psb[MM + m], sz = psb[2 * MM + m];
    float ss  = sx * sx + sy * sy + sz * sz;
    float dot = qx * sx + qy * sy + qz * sz;
    float d2  = qq + ss - 2.f * dot;
    unsigned int bu = __float_as_uint(d2);
    bu = (bu & 0x80000000u) ? ~bu : (bu | 0x80000000u);   // order-preserving map
    unsigned long long pk = (((unsigned long long)bu) << 32) | (unsigned int)m;
    if (pk < list[15]) {
      list[15] = pk;
      #pragma unroll
      for (int j = 15; j > 0; --j) {
        unsigned long long a = list[j - 1], c = list[j];
        list[j - 1] = c < a ? c : a;
        list[j]     = c < a ? a : c;
      }
    }
  }
  #pragma unroll
  for (int i = 0; i < 16; ++i) cand[w][lane * 16 + i] = list[i];
  int head = 0;
  for (int r = 0; r < 16; ++r) {
    unsigned long long v = (head < 16) ? cand[w][lane * 16 + head] : ~0ULL;
    unsigned long long mv = v;
    #pragma unroll
    for (int off = 32; off > 0; off >>= 1) {
      unsigned long long o = __shfl_xor(mv, off, 64);
      mv = o < mv ? o : mv;
    }
    if (v == mv) head++;
    if (lane == 0) idxb[qi * 16 + r] = (int)(mv & 0xFFFFFFFFu);
  }
}

// ---------------------------------------------------------------------------
// pos_rel first/second moments (3 + 6 values) -> stat[0..8]
// ---------------------------------------------------------------------------
__global__ __launch_bounds__(256) void k_posstats(
    const float* __restrict__ pq, const float* __restrict__ ps,
    const int* __restrict__ idxb, float* __restrict__ stat) {
  int gid = blockIdx.x * 256 + threadIdx.x;   // 131072
  int b = gid >> 15;
  int n = (gid >> 4) & 2047;
  int mi = idxb[gid];
  const float* pqb = pq + b * 3 * NN;
  const float* psb = ps + b * 3 * MM;
  float r0 = pqb[n]          - psb[mi];
  float r1 = pqb[NN + n]     - psb[MM + mi];
  float r2 = pqb[2 * NN + n] - psb[2 * MM + mi];
  float vals[9] = {r0, r1, r2, r0*r0, r0*r1, r0*r2, r1*r1, r1*r2, r2*r2};
  #pragma unroll
  for (int i = 0; i < 9; ++i) {
    float v = vals[i];
    #pragma unroll
    for (int off = 32; off > 0; off >>= 1) v += __shfl_xor(v, off, 64);
    if ((threadIdx.x & 63) == 0) atomicAdd(&stat[i], v);
  }
}

// ---------------------------------------------------------------------------
// fold pos-BN into Wp1/bp1  (exact: pe1 is linear in pos_rel)
// ---------------------------------------------------------------------------
__global__ void k_posfinal(
    const float* __restrict__ Wp1, const float* __restrict__ bp1,
    const float* __restrict__ gp, const float* __restrict__ btp,
    const float* __restrict__ stat, float* __restrict__ Wp1f, float* __restrict__ bp1f) {
  int d = threadIdx.x;   // 64
  const float invN = 1.f / (float)NSAMP;
  float m0 = stat[0]*invN, m1 = stat[1]*invN, m2 = stat[2]*invN;
  float C00 = stat[3]*invN - m0*m0, C01 = stat[4]*invN - m0*m1, C02 = stat[5]*invN - m0*m2;
  float C11 = stat[6]*invN - m1*m1, C12 = stat[7]*invN - m1*m2, C22 = stat[8]*invN - m2*m2;
  float w0 = Wp1[d*3], w1 = Wp1[d*3+1], w2 = Wp1[d*3+2];
  float mean = w0*m0 + w1*m1 + w2*m2 + bp1[d];
  float var = w0*w0*C00 + w1*w1*C11 + w2*w2*C22 + 2.f*(w0*w1*C01 + w0*w2*C02 + w1*w2*C12);
  float scale = gp[d] * rsqrtf(var + 1e-5f);
  Wp1f[d*3]   = scale * w0;
  Wp1f[d*3+1] = scale * w1;
  Wp1f[d*3+2] = scale * w2;
  bp1f[d] = btp[d] + scale * (bp1[d] - mean);
}

// ---------------------------------------------------------------------------
// y = q - k_g + pe  first/second moments:  ySum[64], Gram G[64][64]
// ---------------------------------------------------------------------------
__global__ __launch_bounds__(256) void k_ystats(
    const float* __restrict__ pq, const float* __restrict__ ps,
    const float* __restrict__ qT, const float* __restrict__ kT,
    const int* __restrict__ idxb,
    const float* __restrict__ Wp1f, const float* __restrict__ bp1f,
    const float* __restrict__ Wp2t, const float* __restrict__ bp2,
    float* __restrict__ ySum, float* __restrict__ G) {
  __shared__ __attribute__((aligned(16))) float hp[64 * 20];
  __shared__ __attribute__((aligned(16))) float yt[64 * 20];
  __shared__ float r3[48];
  __shared__ float qc[64];
  __shared__ int   idx16[16];
  int t = threadIdx.x;
  int d = t >> 2, kb = (t & 3) * 4;
  int gi = t >> 2, gj = (t & 3) * 16;
  float pw0 = Wp1f[d*3], pw1 = Wp1f[d*3+1], pw2 = Wp1f[d*3+2], pb = bp1f[d];
  float bp2v = bp2[d];
  float gacc[16];
  #pragma unroll
  for (int e = 0; e < 16; ++e) gacc[e] = 0.f;
  float ysacc = 0.f;
  for (int pp = 0; pp < 32; ++pp) {
    int p = blockIdx.x * 32 + pp;   // grid 256
    int b = p >> 11, n = p & 2047;
    __syncthreads();
    if (t < 16) idx16[t] = idxb[p * 16 + t];
    if (t >= 64 && t < 128) qc[t - 64] = qT[p * 64 + (t - 64)];
    __syncthreads();
    if (t < 48) { int c = t >> 4, k = t & 15;
      r3[c * 16 + k] = pq[(b*3 + c)*NN + n] - ps[(b*3 + c)*MM + idx16[k]]; }
    __syncthreads();
    #pragma unroll
    for (int e = 0; e < 4; ++e) { int k = kb + e;
      float v = pb + pw0 * r3[k] + pw1 * r3[16 + k] + pw2 * r3[32 + k];
      hp[d * 20 + k] = v > 0.f ? v : 0.f; }
    __syncthreads();
    int mi0 = idx16[kb], mi1 = idx16[kb+1], mi2 = idx16[kb+2], mi3 = idx16[kb+3];
    const float* kbase = kT + (b * NN) * 64 + d;
    float kg0 = kbase[mi0*64], kg1 = kbase[mi1*64], kg2 = kbase[mi2*64], kg3 = kbase[mi3*64];
    float a0 = bp2v, a1 = bp2v, a2 = bp2v, a3 = bp2v;
    #pragma unroll 8
    for (int i = 0; i < 64; ++i) {
      float w = Wp2t[i * 64 + d];
      float4 h = *(const float4*)&hp[i * 20 + kb];
      a0 = fmaf(w, h.x, a0); a1 = fmaf(w, h.y, a1);
      a2 = fmaf(w, h.z, a2); a3 = fmaf(w, h.w, a3);
    }
    float qv = qc[d];
    yt[d*20 + kb]     = qv - kg0 + a0;
    yt[d*20 + kb + 1] = qv - kg1 + a1;
    yt[d*20 + kb + 2] = qv - kg2 + a2;
    yt[d*20 + kb + 3] = qv - kg3 + a3;
    __syncthreads();
    float4 yi0 = *(const float4*)&yt[gi*20];
    float4 yi1 = *(const float4*)&yt[gi*20 + 4];
    float4 yi2 = *(const float4*)&yt[gi*20 + 8];
    float4 yi3 = *(const float4*)&yt[gi*20 + 12];
    #pragma unroll
    for (int e = 0; e < 16; ++e) {
      const float* yr = &yt[(gj + e) * 20];
      float4 z0 = *(const float4*)yr, z1 = *(const float4*)(yr+4);
      float4 z2 = *(const float4*)(yr+8), z3 = *(const float4*)(yr+12);
      float a = gacc[e];
      a = fmaf(yi0.x, z0.x, a); a = fmaf(yi0.y, z0.y, a);
      a = fmaf(yi0.z, z0.z, a); a = fmaf(yi0.w, z0.w, a);
      a = fmaf(yi1.x, z1.x, a); a = fmaf(yi1.y, z1.y, a);
      a = fmaf(yi1.z, z1.z, a); a = fmaf(yi1.w, z1.w, a);
      a = fmaf(yi2.x, z2.x, a); a = fmaf(yi2.y, z2.y, a);
      a = fmaf(yi2.z, z2.z, a); a = fmaf(yi2.w, z2.w, a);
      a = fmaf(yi3.x, z3.x, a); a = fmaf(yi3.y, z3.y, a);
      a = fmaf(yi3.z, z3.z, a); a = fmaf(yi3.w, z3.w, a);
      gacc[e] = a;
    }
    if (t < 64) {
      const float* yr = &yt[t * 20];
      float4 z0 = *(const float4*)yr, z1 = *(const float4*)(yr+4);
      float4 z2 = *(const float4*)(yr+8), z3 = *(const float4*)(yr+12);
      ysacc += z0.x+z0.y+z0.z+z0.w + z1.x+z1.y+z1.z+z1.w
             + z2.x+z2.y+z2.z+z2.w + z3.x+z3.y+z3.z+z3.w;
    }
  }
  #pragma unroll
  for (int e = 0; e < 16; ++e) atomicAdd(&G[gi * 64 + gj + e], gacc[e]);
  if (t < 64) atomicAdd(&ySum[t], ysacc);
}

// ---------------------------------------------------------------------------
// fold attn-BN into Wa1/ba1 via mean/Gram  (exact: a1 linear in y)
// ---------------------------------------------------------------------------
__global__ __launch_bounds__(256) void k_attnfinal(
    const float* __restrict__ Wa1, const float* __restrict__ ba1,
    const float* __restrict__ ga, const float* __restrict__ bta,
    const float* __restrict__ ySum, const float* __restrict__ G,
    float* __restrict__ Wa1f, float* __restrict__ ba1f) {
  __shared__ float red[256];
  __shared__ float mu[64];
  __shared__ float sc[1];
  int h = blockIdx.x, t = threadIdx.x;
  const float invN = 1.f / (float)NSAMP;
  if (t < 64) mu[t] = ySum[t] * invN;
  __syncthreads();
  float acc = 0.f;
  #pragma unroll
  for (int e = 0; e < 16; ++e) {
    int pi = t * 16 + e, i = pi >> 6, j = pi & 63;
    float cov = G[pi] * invN - mu[i] * mu[j];
    acc += Wa1[h * 64 + i] * Wa1[h * 64 + j] * cov;
  }
  red[t] = acc;
  __syncthreads();
  for (int s = 128; s > 0; s >>= 1) { if (t < s) red[t] += red[t + s]; __syncthreads(); }
  float var = red[0];
  __syncthreads();
  red[t] = (t < 64) ? Wa1[h * 64 + t] * mu[t] : 0.f;
  __syncthreads();
  for (int s = 128; s > 0; s >>= 1) { if (t < s) red[t] += red[t + s]; __syncthreads(); }
  if (t == 0) {
    float mean  = red[0] + ba1[h];
    float scale = ga[h] * rsqrtf(var + 1e-5f);
    sc[0] = scale;
    ba1f[h] = bta[h] + scale * (ba1[h] - mean);
  }
  __syncthreads();
  if (t < 64) Wa1f[h * 64 + t] = sc[0] * Wa1[h * 64 + t];
}

// ---------------------------------------------------------------------------
// main fused kernel: per point -> pos MLP, y, a1(relu), a2, softmax, agg
// ---------------------------------------------------------------------------
__global__ __launch_bounds__(256) void k_main(
    const float* __restrict__ pq, const float* __restrict__ ps,
    const float* __restrict__ qT, const float* __restrict__ kT, const float* __restrict__ vT,
    const int* __restrict__ idxb,
    const float* __restrict__ Wp1f, const float* __restrict__ bp1f,
    const float* __restrict__ Wp2t, const float* __restrict__ bp2,
    const float* __restrict__ Wa1f, const float* __restrict__ ba1f,
    const float* __restrict__ Wa2t, const float* __restrict__ ba2,
    float* __restrict__ aggT) {
  __shared__ __attribute__((aligned(16))) float hp[64 * 20];
  __shared__ __attribute__((aligned(16))) float yt[64 * 20];
  __shared__ __attribute__((aligned(16))) float vt[64 * 20];
  __shared__ __attribute__((aligned(16))) float at[64 * 20];
  __shared__ __attribute__((aligned(16))) float ha[256 * 20];
  __shared__ __attribute__((aligned(16))) float ap[4 * 64 * 20];
  __shared__ float r3[48];
  __shared__ float qc[64];
  __shared__ int   idx16[16];
  int t = threadIdx.x;
  int wv = t >> 6, lane = t & 63;
  int d = t >> 2, kb = (t & 3) * 4;
  float wrow[64];
  #pragma unroll
  for (int i = 0; i < 64; ++i) wrow[i] = Wa1f[t * 64 + i];
  float ba1v = ba1f[t];
  float pw0 = Wp1f[d*3], pw1 = Wp1f[d*3+1], pw2 = Wp1f[d*3+2], pb = bp1f[d];
  float bp2v = bp2[d];
  float ba2d = ba2[d];
  for (int pp = 0; pp < 16; ++pp) {
    int p = blockIdx.x * 16 + pp;    // grid 512
    int b = p >> 11, n = p & 2047;
    __syncthreads();
    if (t < 16) idx16[t] = idxb[p * 16 + t];
    if (t >= 64 && t < 128) qc[t - 64] = qT[p * 64 + (t - 64)];
    __syncthreads();
    if (t < 48) { int c = t >> 4, k = t & 15;
      r3[c * 16 + k] = pq[(b*3 + c)*NN + n] - ps[(b*3 + c)*MM + idx16[k]]; }
    __syncthreads();
    #pragma unroll
    for (int e = 0; e < 4; ++e) { int k = kb + e;
      float v = pb + pw0 * r3[k] + pw1 * r3[16 + k] + pw2 * r3[32 + k];
      hp[d * 20 + k] = v > 0.f ? v : 0.f; }
    __syncthreads();
    // ---- pe, y, val ----
    int mi0 = idx16[kb], mi1 = idx16[kb+1], mi2 = idx16[kb+2], mi3 = idx16[kb+3];
    const float* kbase = kT + (b * NN) * 64 + d;
    const float* vbase = vT + (b * NN) * 64 + d;
    float kg0 = kbase[mi0*64], kg1 = kbase[mi1*64], kg2 = kbase[mi2*64], kg3 = kbase[mi3*64];
    float vg0 = vbase[mi0*64], vg1 = vbase[mi1*64], vg2 = vbase[mi2*64], vg3 = vbase[mi3*64];
    float a0 = bp2v, a1 = bp2v, a2 = bp2v, a3 = bp2v;
    #pragma unroll 8
    for (int i = 0; i < 64; ++i) {
      float w = Wp2t[i * 64 + d];
      float4 h = *(const float4*)&hp[i * 20 + kb];
      a0 = fmaf(w, h.x, a0); a1 = fmaf(w, h.y, a1);
      a2 = fmaf(w, h.z, a2); a3 = fmaf(w, h.w, a3);
    }
    float qv = qc[d];
    yt[d*20 + kb]     = qv - kg0 + a0;  vt[d*20 + kb]     = vg0 + a0;
    yt[d*20 + kb + 1] = qv - kg1 + a1;  vt[d*20 + kb + 1] = vg1 + a1;
    yt[d*20 + kb + 2] = qv - kg2 + a2;  vt[d*20 + kb + 2] = vg2 + a2;
    yt[d*20 + kb + 3] = qv - kg3 + a3;  vt[d*20 + kb + 3] = vg3 + a3;
    __syncthreads();
    // ---- a1 = Wa1f @ y (+ba1f), relu -> ha[j][k] ----
    float aa[16];
    #pragma unroll
    for (int k = 0; k < 16; ++k) aa[k] = 0.f;
    #pragma unroll
    for (int i = 0; i < 64; ++i) {
      float w = wrow[i];
      float4 y0 = *(const float4*)&yt[i*20];
      float4 y1 = *(const float4*)&yt[i*20 + 4];
      float4 y2 = *(const float4*)&yt[i*20 + 8];
      float4 y3 = *(const float4*)&yt[i*20 + 12];
      aa[0]  = fmaf(w, y0.x, aa[0]);  aa[1]  = fmaf(w, y0.y, aa[1]);
      aa[2]  = fmaf(w, y0.z, aa[2]);  aa[3]  = fmaf(w, y0.w, aa[3]);
      aa[4]  = fmaf(w, y1.x, aa[4]);  aa[5]  = fmaf(w, y1.y, aa[5]);
      aa[6]  = fmaf(w, y1.z, aa[6]);  aa[7]  = fmaf(w, y1.w, aa[7]);
      aa[8]  = fmaf(w, y2.x, aa[8]);  aa[9]  = fmaf(w, y2.y, aa[9]);
      aa[10] = fmaf(w, y2.z, aa[10]); aa[11] = fmaf(w, y2.w, aa[11]);
      aa[12] = fmaf(w, y3.x, aa[12]); aa[13] = fmaf(w, y3.y, aa[13]);
      aa[14] = fmaf(w, y3.z, aa[14]); aa[15] = fmaf(w, y3.w, aa[15]);
    }
    #pragma unroll
    for (int k = 0; k < 16; ++k) {
      float hv = aa[k] + ba1v;
      ha[t * 20 + k] = hv > 0.f ? hv : 0.f;
    }
    __syncthreads();
    // ---- a2 partial: wave wv covers j in [wv*64, wv*64+64), d = lane ----
    {
      float cc[16];
      #pragma unroll
      for (int k = 0; k < 16; ++k) cc[k] = 0.f;
      int j0 = wv * 64;
      const float* wbase = Wa2t + j0 * 64 + lane;
      #pragma unroll 8
      for (int jj = 0; jj < 64; ++jj) {
        float w = wbase[jj * 64];
        int j = j0 + jj;
        float4 h0 = *(const float4*)&ha[j*20];
        float4 h1 = *(const float4*)&ha[j*20 + 4];
        float4 h2 = *(const float4*)&ha[j*20 + 8];
        float4 h3 = *(const float4*)&ha[j*20 + 12];
        cc[0]  = fmaf(w, h0.x, cc[0]);  cc[1]  = fmaf(w, h0.y, cc[1]);
        cc[2]  = fmaf(w, h0.z, cc[2]);  cc[3]  = fmaf(w, h0.w, cc[3]);
        cc[4]  = fmaf(w, h1.x, cc[4]);  cc[5]  = fmaf(w, h1.y, cc[5]);
        cc[6]  = fmaf(w, h1.z, cc[6]);  cc[7]  = fmaf(w, h1.w, cc[7]);
        cc[8]  = fmaf(w, h2.x, cc[8]);  cc[9]  = fmaf(w, h2.y, cc[9]);
        cc[10] = fmaf(w, h2.z, cc[10]); cc[11] = fmaf(w, h2.w, cc[11]);
        cc[12] = fmaf(w, h3.x, cc[12]); cc[13] = fmaf(w, h3.y, cc[13]);
        cc[14] = fmaf(w, h3.z, cc[14]); cc[15] = fmaf(w, h3.w, cc[15]);
      }
      #pragma unroll
      for (int k = 0; k < 16; ++k) ap[wv * 1280 + lane * 20 + k] = cc[k];
    }
    __syncthreads();
    #pragma unroll
    for (int e = 0; e < 4; ++e) {
      int k = kb + e;
      float s = ap[d*20 + k] + ap[1280 + d*20 + k] + ap[2560 + d*20 + k] + ap[3840 + d*20 + k];
      at[d * 20 + k] = s + ba2d;
    }
    __syncthreads();
    // ---- softmax over K + weighted sum of val ----
    if (t < 64) {
      float4 x0 = *(const float4*)&at[t*20];
      float4 x1 = *(const float4*)&at[t*20 + 4];
      float4 x2 = *(const float4*)&at[t*20 + 8];
      float4 x3 = *(const float4*)&at[t*20 + 12];
      float mx = fmaxf(fmaxf(fmaxf(x0.x,x0.y),fmaxf(x0.z,x0.w)),
                       fmaxf(fmaxf(x1.x,x1.y),fmaxf(x1.z,x1.w)));
      mx = fmaxf(mx, fmaxf(fmaxf(fmaxf(x2.x,x2.y),fmaxf(x2.z,x2.w)),
                           fmaxf(fmaxf(x3.x,x3.y),fmaxf(x3.z,x3.w))));
      float e0 = __expf(x0.x-mx), e1 = __expf(x0.y-mx), e2 = __expf(x0.z-mx), e3 = __expf(x0.w-mx);
      float e4 = __expf(x1.x-mx), e5 = __expf(x1.y-mx), e6 = __expf(x1.z-mx), e7 = __expf(x1.w-mx);
      float e8 = __expf(x2.x-mx), e9 = __expf(x2.y-mx), e10= __expf(x2.z-mx), e11= __expf(x2.w-mx);
      float e12= __expf(x3.x-mx), e13= __expf(x3.y-mx), e14= __expf(x3.z-mx), e15= __expf(x3.w-mx);
      float s = e0+e1+e2+e3+e4+e5+e6+e7+e8+e9+e10+e11+e12+e13+e14+e15;
      float4 v0 = *(const float4*)&vt[t*20];
      float4 v1 = *(const float4*)&vt[t*20 + 4];
      float4 v2 = *(const float4*)&vt[t*20 + 8];
      float4 v3 = *(const float4*)&vt[t*20 + 12];
      float num = e0*v0.x + e1*v0.y + e2*v0.z + e3*v0.w
                + e4*v1.x + e5*v1.y + e6*v1.z + e7*v1.w
                + e8*v2.x + e9*v2.y + e10*v2.z + e11*v2.w
                + e12*v3.x + e13*v3.y + e14*v3.z + e15*v3.w;
      aggT[p * 64 + t] = num / s;
    }
    __syncthreads();
  }
}

// ---------------------------------------------------------------------------
// epilogue: out[b,c,n] = We[c,:]·agg[b,:,n] + be[c] + fq[b,c,n]
// ---------------------------------------------------------------------------
__global__ __launch_bounds__(256) void k_epilogue(
    const float* __restrict__ aggT, const float* __restrict__ We,
    const float* __restrict__ be, const float* __restrict__ fq, float* __restrict__ out) {
  int bid = blockIdx.x;               // 4 * 32 * 32 = 4096
  int b  = bid >> 10;
  int c0 = ((bid >> 5) & 31) * 4;
  int n0 = (bid & 31) * 64;
  int t = threadIdx.x;
  int n = n0 + (t & 63), c = c0 + (t >> 6);
  float acc = be[c];
  const float* ag = aggT + (b * NN + n) * 64;
  const float* wr = We + c * 64;
  #pragma unroll 8
  for (int dd = 0; dd < 64; ++dd) acc = fmaf(wr[dd], ag[dd], acc);
  int o = (b * CC + c) * NN + n;
  out[o] = acc + fq[o];
}

// ---------------------------------------------------------------------------
extern "C" void kernel_launch(void* const* d_in, const int* in_sizes, int n_in,
                              void* d_out, int out_size, void* d_ws, size_t ws_size,
                              hipStream_t stream) {
  (void)in_sizes; (void)n_in; (void)out_size; (void)ws_size;
  const float* pq  = (const float*)d_in[0];
  const float* fq  = (const float*)d_in[1];
  const float* ps  = (const float*)d_in[2];
  const float* fs  = (const float*)d_in[3];
  const float* Wq  = (const float*)d_in[4];  const float* bq  = (const float*)d_in[5];
  const float* Wk  = (const float*)d_in[6];  const float* bk  = (const float*)d_in[7];
  const float* Wv  = (const float*)d_in[8];  const float* bv  = (const float*)d_in[9];
  const float* Wp1 = (const float*)d_in[10]; const float* bp1 = (const float*)d_in[11];
  const float* gp  = (const float*)d_in[12]; const float* btp = (const float*)d_in[13];
  const float* Wp2 = (const float*)d_in[14]; const float* bp2 = (const float*)d_in[15];
  const float* Wa1 = (const float*)d_in[16]; const float* ba1 = (const float*)d_in[17];
  const float* ga  = (const float*)d_in[18]; const float* bta = (const float*)d_in[19];
  const float* Wa2 = (const float*)d_in[20]; const float* ba2 = (const float*)d_in[21];
  const float* We  = (const float*)d_in[22]; const float* be  = (const float*)d_in[23];
  float* ws = (float*)d_ws;
  float* qT   = ws;
  float* kT   = ws + 524288;
  float* vT   = ws + 1048576;
  float* aggT = ws + 1572864;
  int*   idxb = (int*)(ws + 2097152);
  float* Wqt  = ws + 2228224;
  float* Wkt  = ws + 2236416;
  float* Wvt  = ws + 2244608;
  float* Wp2t = ws + 2252800;
  float* Wa2t = ws + 2256896;
  float* Wp1f = ws + 2273280;
  float* bp1f = ws + 2273472;
  float* Wa1f = ws + 2273536;
  float* ba1f = ws + 2289920;
  float* stat = ws + 2290176;     // 9 (+pad to 16)
  float* ySum = stat + 16;        // 64
  float* G    = stat + 80;        // 4096
  float* out  = (float*)d_out;

  k_prep<<<64, 256, 0, stream>>>(Wq, Wk, Wv, Wp2, Wa2, Wqt, Wkt, Wvt, Wp2t, Wa2t, stat);
  k_qkv<<<3072, 256, 0, stream>>>(fq, fs, Wqt, Wkt, Wvt, bq, bk, bv, qT, kT, vT);
  k_knn<<<2048, 256, 0, stream>>>(pq, ps, idxb);
  k_posstats<<<512, 256, 0, stream>>>(pq, ps, idxb, stat);
  k_posfinal<<<1, 64, 0, stream>>>(Wp1, bp1, gp, btp, stat, Wp1f, bp1f);
  k_ystats<<<256, 256, 0, stream>>>(pq, ps, qT, kT, idxb, Wp1f, bp1f, Wp2t, bp2, ySum, G);
  k_attnfinal<<<256, 256, 0, stream>>>(Wa1, ba1, ga, bta, ySum, G, Wa1f, ba1f);
  k_main<<<512, 256, 0, stream>>>(pq, ps, qT, kT, vT, idxb, Wp1f, bp1f, Wp2t, bp2,
                                  Wa1f, ba1f, Wa2t, ba2, aggT);
  k_epilogue<<<4096, 256, 0, stream>>>(aggT, We, be, fq, out);
}

// Round 2
// 579.019 us; speedup vs baseline: 2.3980x; 2.3980x over previous
//
#include <hip/hip_runtime.h>
#include <stdint.h>

#define NN 2048
#define MM 2048
#define NSAMP 131072   // B*N*K

typedef float  fv4 __attribute__((ext_vector_type(4)));
typedef short  bfv8 __attribute__((ext_vector_type(8)));
typedef short  bfv4 __attribute__((ext_vector_type(4)));
typedef unsigned short u16;

__device__ inline u16 f2bf(float x){
  unsigned u = __float_as_uint(x);
  return (u16)((u + 0x7FFFu + ((u>>16)&1u)) >> 16);
}
__device__ inline float bf2f(u16 u){ return __uint_as_float(((unsigned)u)<<16); }
#define MFMA16 __builtin_amdgcn_mfma_f32_16x16x32_bf16

// ---------------------------------------------------------------------------
// prep: transpose qkv weights + bf16-pack Wp2 (row-major d,i) and Wa2 (d,h);
// zero the pos-stats accumulator.
// ---------------------------------------------------------------------------
__global__ __launch_bounds__(256) void k_prep(
    const float* __restrict__ Wq, const float* __restrict__ Wk, const float* __restrict__ Wv,
    const float* __restrict__ Wp2, const float* __restrict__ Wa2,
    float* __restrict__ Wqt, float* __restrict__ Wkt, float* __restrict__ Wvt,
    u16* __restrict__ Wp2bf, u16* __restrict__ Wa2bf, float* __restrict__ statz) {
  int gid = blockIdx.x * 256 + threadIdx.x;   // grid 64*256 = 16384
  if (gid < 8192)  { int c = gid >> 6, d = gid & 63;
    Wqt[gid] = Wq[d*128 + c]; Wkt[gid] = Wk[d*128 + c]; Wvt[gid] = Wv[d*128 + c]; }
  if (gid < 4096)  Wp2bf[gid] = f2bf(Wp2[gid]);     // (D,D) row-major
  if (gid < 16384) Wa2bf[gid] = f2bf(Wa2[gid]);     // (D,H) row-major
  if (gid < 64)    statz[gid] = 0.f;
}

// ---------------------------------------------------------------------------
// q/k/v 1x1 conv -> n-major (point,d) layout
// ---------------------------------------------------------------------------
__global__ __launch_bounds__(256) void k_qkv(
    const float* __restrict__ fq, const float* __restrict__ fs,
    const float* __restrict__ Wqt, const float* __restrict__ Wkt, const float* __restrict__ Wvt,
    const float* __restrict__ bq, const float* __restrict__ bk, const float* __restrict__ bv,
    float* __restrict__ qT, float* __restrict__ kT, float* __restrict__ vT) {
  int bid = blockIdx.x;              // 3 * 4 * 256 = 3072
  int mat = bid >> 10;
  int rem = bid & 1023;
  int b  = rem >> 8;
  int n0 = (rem & 255) * 8;
  int t = threadIdx.x, d = t & 63, pc = t >> 6;
  const float* W   = mat == 0 ? Wqt : (mat == 1 ? Wkt : Wvt);
  const float* src = mat == 0 ? fq  : fs;
  const float* bia = mat == 0 ? bq  : (mat == 1 ? bk : bv);
  float* dst = mat == 0 ? qT : (mat == 1 ? kT : vT);
  int n_a = n0 + pc, n_b = n0 + 4 + pc;
  const float* sa = src + b * 128 * NN;
  float acc0 = bia[d], acc1 = acc0;
  #pragma unroll 8
  for (int c = 0; c < 128; ++c) {
    float w = W[c * 64 + d];
    acc0 = fmaf(w, sa[c * NN + n_a], acc0);
    acc1 = fmaf(w, sa[c * NN + n_b], acc1);
  }
  dst[(b * NN + n_a) * 64 + d] = acc0;
  dst[(b * NN + n_b) * 64 + d] = acc1;
}

// ---------------------------------------------------------------------------
// KNN: one wave per query (unchanged from round 1)
// ---------------------------------------------------------------------------
__global__ __launch_bounds__(256) void k_knn(
    const float* __restrict__ pq, const float* __restrict__ ps, int* __restrict__ idxb) {
  __shared__ unsigned long long cand[4][64 * 16];
  int t = threadIdx.x, w = t >> 6, lane = t & 63;
  int qi = blockIdx.x * 4 + w;       // 0..8191
  int b = qi >> 11, n = qi & 2047;
  const float* pqb = pq + b * 3 * NN;
  const float* psb = ps + b * 3 * MM;
  float qx = pqb[n], qy = pqb[NN + n], qz = pqb[2 * NN + n];
  float qq = qx * qx + qy * qy + qz * qz;
  unsigned long long list[16];
  #pragma unroll
  for (int i = 0; i < 16; ++i) list[i] = ~0ULL;
  for (int m = lane; m < MM; m += 64) {
    float sx = psb[m], sy = psb[MM + m], sz = psb[2 * MM + m];
    float ss  = sx * sx + sy * sy + sz * sz;
    float dot = qx * sx + qy * sy + qz * sz;
    float d2  = qq + ss - 2.f * dot;
    unsigned int bu = __float_as_uint(d2);
    bu = (bu & 0x80000000u) ? ~bu : (bu | 0x80000000u);
    unsigned long long pk = (((unsigned long long)bu) << 32) | (unsigned int)m;
    if (pk < list[15]) {
      list[15] = pk;
      #pragma unroll
      for (int j = 15; j > 0; --j) {
        unsigned long long a = list[j - 1], c = list[j];
        list[j - 1] = c < a ? c : a;
        list[j]     = c < a ? a : c;
      }
    }
  }
  #pragma unroll
  for (int i = 0; i < 16; ++i) cand[w][lane * 16 + i] = list[i];
  int head = 0;
  for (int r = 0; r < 16; ++r) {
    unsigned long long v = (head < 16) ? cand[w][lane * 16 + head] : ~0ULL;
    unsigned long long mv = v;
    #pragma unroll
    for (int off = 32; off > 0; off >>= 1) {
      unsigned long long o = __shfl_xor(mv, off, 64);
      mv = o < mv ? o : mv;
    }
    if (v == mv) head++;
    if (lane == 0) idxb[qi * 16 + r] = (int)(mv & 0xFFFFFFFFu);
  }
}

// ---------------------------------------------------------------------------
// pos_rel first/second moments -> stat[0..8] (small, atomics OK)
// ---------------------------------------------------------------------------
__global__ __launch_bounds__(256) void k_posstats(
    const float* __restrict__ pq, const float* __restrict__ ps,
    const int* __restrict__ idxb, float* __restrict__ stat) {
  int gid = blockIdx.x * 256 + threadIdx.x;   // 131072
  int b = gid >> 15;
  int n = (gid >> 4) & 2047;
  int mi = idxb[gid];
  const float* pqb = pq + b * 3 * NN;
  const float* psb = ps + b * 3 * MM;
  float r0 = pqb[n]          - psb[mi];
  float r1 = pqb[NN + n]     - psb[MM + mi];
  float r2 = pqb[2 * NN + n] - psb[2 * MM + mi];
  float vals[9] = {r0, r1, r2, r0*r0, r0*r1, r0*r2, r1*r1, r1*r2, r2*r2};
  #pragma unroll
  for (int i = 0; i < 9; ++i) {
    float v = vals[i];
    #pragma unroll
    for (int off = 32; off > 0; off >>= 1) v += __shfl_xor(v, off, 64);
    if ((threadIdx.x & 63) == 0) atomicAdd(&stat[i], v);
  }
}

// ---------------------------------------------------------------------------
// fold pos-BN into Wp1/bp1 (exact)
// ---------------------------------------------------------------------------
__global__ void k_posfinal(
    const float* __restrict__ Wp1, const float* __restrict__ bp1,
    const float* __restrict__ gp, const float* __restrict__ btp,
    const float* __restrict__ stat, float* __restrict__ Wp1f, float* __restrict__ bp1f) {
  int d = threadIdx.x;   // 64
  const float invN = 1.f / (float)NSAMP;
  float m0 = stat[0]*invN, m1 = stat[1]*invN, m2 = stat[2]*invN;
  float C00 = stat[3]*invN - m0*m0, C01 = stat[4]*invN - m0*m1, C02 = stat[5]*invN - m0*m2;
  float C11 = stat[6]*invN - m1*m1, C12 = stat[7]*invN - m1*m2, C22 = stat[8]*invN - m2*m2;
  float w0 = Wp1[d*3], w1 = Wp1[d*3+1], w2 = Wp1[d*3+2];
  float mean = w0*m0 + w1*m1 + w2*m2 + bp1[d];
  float var = w0*w0*C00 + w1*w1*C11 + w2*w2*C22 + 2.f*(w0*w1*C01 + w0*w2*C02 + w1*w2*C12);
  float scale = gp[d] * rsqrtf(var + 1e-5f);
  Wp1f[d*3]   = scale * w0;
  Wp1f[d*3+1] = scale * w1;
  Wp1f[d*3+2] = scale * w2;
  bp1f[d] = btp[d] + scale * (bp1[d] - mean);
}

// ---------------------------------------------------------------------------
// y-stats: per-block Gram via MFMA (Y Y^T), partials to Gpart (= d_out scratch)
// grid 256, 32 points/block (8 chunks of 4 points).
// ---------------------------------------------------------------------------
__global__ __launch_bounds__(256) void k_ystats(
    const float* __restrict__ pq, const float* __restrict__ ps,
    const float* __restrict__ qT, const float* __restrict__ kT,
    const int* __restrict__ idxb,
    const float* __restrict__ Wp1f, const float* __restrict__ bp1f,
    const u16* __restrict__ Wp2bf, const float* __restrict__ bp2,
    float* __restrict__ Gpart, float* __restrict__ ySumPart) {
  __shared__ __align__(16) unsigned char smem[21760];
  u16*   hp   = (u16*)smem;                 // [64 s][72 i] bf16
  u16*   y2   = (u16*)(smem + 9216);        // [64 d][72 s] bf16
  float* r3   = (float*)(smem + 18432);     // 192
  float* qc   = (float*)(smem + 19200);     // 256
  int*   idxA = (int*)(smem + 20224);       // 64
  float* sWp1 = (float*)(smem + 20480);     // 192
  float* sbp1 = (float*)(smem + 21248);     // 64
  float* sbp2 = (float*)(smem + 21504);     // 64

  const int t = threadIdx.x;
  const int w = t >> 6, l = t & 63, lq = l >> 4, ln = l & 15;
  const int d0 = 16*w + lq*4;

  if (t < 192) sWp1[t] = Wp1f[t];
  if (t < 64){ sbp1[t] = bp1f[t]; sbp2[t] = bp2[t]; }

  bfv8 Ape[2];
  #pragma unroll
  for (int kk = 0; kk < 2; ++kk)
    Ape[kk] = *(const bfv8*)(Wp2bf + (16*w + ln)*64 + kk*32 + lq*8);

  fv4 gacc[4];
  #pragma unroll
  for (int nt = 0; nt < 4; ++nt) gacc[nt] = (fv4){0.f,0.f,0.f,0.f};
  float ysacc = 0.f;
  __syncthreads();

  for (int ch = 0; ch < 8; ++ch) {
    const int p0 = blockIdx.x * 32 + ch * 4;
    const int b  = p0 >> 11;
    const int bN = b * 2048;
    if (t < 64) idxA[t] = idxb[p0*16 + t];
    qc[t] = qT[(p0 + (t>>6))*64 + (t & 63)];
    __syncthreads();
    if (t < 192) { int c = t >> 6, s = t & 63; int n = (p0 + (s>>4)) & 2047;
      r3[c*64 + s] = pq[(b*3+c)*NN + n] - ps[(b*3+c)*MM + idxA[s]]; }
    __syncthreads();
    { int s = t >> 2, iq = t & 3;
      float r0 = r3[s], r1 = r3[64+s], r2 = r3[128+s];
      u16 tmp[16];
      #pragma unroll
      for (int e = 0; e < 16; ++e) { int i = iq*16 + e;
        float v = sbp1[i] + sWp1[i*3]*r0 + sWp1[i*3+1]*r1 + sWp1[i*3+2]*r2;
        tmp[e] = f2bf(fmaxf(v, 0.f)); }
      *(bfv8*)&hp[s*72 + iq*16]     = *(const bfv8*)&tmp[0];
      *(bfv8*)&hp[s*72 + iq*16 + 8] = *(const bfv8*)&tmp[8];
    }
    __syncthreads();
    {
      fv4 pe[4];
      #pragma unroll
      for (int nt = 0; nt < 4; ++nt) {
        fv4 acc = {0.f,0.f,0.f,0.f};
        #pragma unroll
        for (int kk = 0; kk < 2; ++kk) {
          bfv8 bb = *(const bfv8*)&hp[(nt*16 + ln)*72 + kk*32 + lq*8];
          acc = MFMA16(Ape[kk], bb, acc, 0, 0, 0);
        }
        pe[nt] = acc;
      }
      fv4 bp2q = *(const fv4*)&sbp2[d0];
      #pragma unroll
      for (int nt = 0; nt < 4; ++nt) {
        int s = nt*16 + ln;
        int mi = idxA[s];
        fv4 kg = *(const fv4*)(kT + (bN + mi)*64 + d0);
        fv4 qv = *(const fv4*)&qc[nt*64 + d0];
        fv4 yv = qv - kg + pe[nt] + bp2q;
        #pragma unroll
        for (int r = 0; r < 4; ++r) y2[(d0 + r)*72 + s] = f2bf(yv[r]);
      }
    }
    __syncthreads();
    // Gram: G += Y Y^T  (wave w owns rows [16w,16w+16))
    #pragma unroll
    for (int kk = 0; kk < 2; ++kk) {
      bfv8 aa = *(const bfv8*)&y2[(16*w + ln)*72 + kk*32 + lq*8];
      #pragma unroll
      for (int nt = 0; nt < 4; ++nt) {
        bfv8 bb = *(const bfv8*)&y2[(nt*16 + ln)*72 + kk*32 + lq*8];
        gacc[nt] = MFMA16(aa, bb, gacc[nt], 0, 0, 0);
      }
    }
    if (t < 64) {
      float s = 0.f;
      #pragma unroll
      for (int ss = 0; ss < 64; ++ss) s += bf2f(y2[t*72 + ss]);
      ysacc += s;
    }
    __syncthreads();
  }
  #pragma unroll
  for (int nt = 0; nt < 4; ++nt)
    #pragma unroll
    for (int r = 0; r < 4; ++r)
      Gpart[blockIdx.x*4096 + (16*w + lq*4 + r)*64 + nt*16 + ln] = gacc[nt][r];
  if (t < 64) ySumPart[blockIdx.x*64 + t] = ysacc;
}

// ---------------------------------------------------------------------------
// reduce Gram / ySum partials (no atomics anywhere)
// ---------------------------------------------------------------------------
__global__ __launch_bounds__(256) void k_gred(
    const float* __restrict__ Gpart, const float* __restrict__ ySumPart,
    float* __restrict__ G, float* __restrict__ ySum) {
  int bid = blockIdx.x, t = threadIdx.x;   // grid 17
  if (bid < 16) {
    int j = bid*256 + t;
    float s = 0.f;
    for (int p = 0; p < 256; ++p) s += Gpart[p*4096 + j];
    G[j] = s;
  } else if (t < 64) {
    float s = 0.f;
    for (int p = 0; p < 256; ++p) s += ySumPart[p*64 + t];
    ySum[t] = s;
  }
}

// ---------------------------------------------------------------------------
// fold attn-BN into Wa1/ba1; emit bf16 Wa1f
// ---------------------------------------------------------------------------
__global__ __launch_bounds__(256) void k_attnfinal(
    const float* __restrict__ Wa1, const float* __restrict__ ba1,
    const float* __restrict__ ga, const float* __restrict__ bta,
    const float* __restrict__ ySum, const float* __restrict__ G,
    u16* __restrict__ Wa1fbf, float* __restrict__ ba1f) {
  __shared__ float red[256];
  __shared__ float mu[64];
  __shared__ float sc[1];
  int h = blockIdx.x, t = threadIdx.x;
  const float invN = 1.f / (float)NSAMP;
  if (t < 64) mu[t] = ySum[t] * invN;
  __syncthreads();
  float acc = 0.f;
  #pragma unroll
  for (int e = 0; e < 16; ++e) {
    int pi = t*16 + e, i = pi >> 6, j = pi & 63;
    float cov = G[pi]*invN - mu[i]*mu[j];
    acc += Wa1[h*64 + i] * Wa1[h*64 + j] * cov;
  }
  red[t] = acc;
  __syncthreads();
  for (int s = 128; s > 0; s >>= 1) { if (t < s) red[t] += red[t + s]; __syncthreads(); }
  float var = red[0];
  __syncthreads();
  red[t] = (t < 64) ? Wa1[h*64 + t] * mu[t] : 0.f;
  __syncthreads();
  for (int s = 128; s > 0; s >>= 1) { if (t < s) red[t] += red[t + s]; __syncthreads(); }
  if (t == 0) {
    float mean  = red[0] + ba1[h];
    float scale = ga[h] * rsqrtf(var + 1e-5f);
    sc[0] = scale;
    ba1f[h] = bta[h] + scale * (ba1[h] - mean);
  }
  __syncthreads();
  if (t < 64) Wa1fbf[h*64 + t] = f2bf(sc[0] * Wa1[h*64 + t]);
}

// ---------------------------------------------------------------------------
// main fused kernel (MFMA): per 4-point chunk: pe GEMM, y/val, a1 GEMM(relu),
// a2 GEMM, softmax+agg. grid 1024, 8 pts/block.
// ---------------------------------------------------------------------------
__global__ __launch_bounds__(256) void k_main(
    const float* __restrict__ pq, const float* __restrict__ ps,
    const float* __restrict__ qT, const float* __restrict__ kT, const float* __restrict__ vT,
    const int* __restrict__ idxb,
    const float* __restrict__ Wp1f, const float* __restrict__ bp1f,
    const u16* __restrict__ Wp2bf, const float* __restrict__ bp2,
    const u16* __restrict__ Wa1fbf, const float* __restrict__ ba1f,
    const u16* __restrict__ Wa2bf, const float* __restrict__ ba2,
    float* __restrict__ aggT) {
  __shared__ __align__(16) unsigned char smem[65024];
  u16*   hp   = (u16*)smem;                    // [64 s][72 i] bf16 (aliases ha)
  u16*   ha   = (u16*)smem;                    // [64 s][264 h] bf16
  u16*   ylds = (u16*)(smem + 33792);          // [64 s][72 d] bf16 (aliases at)
  float* at   = (float*)(smem + 33792);        // [64 s][68 d] f32
  u16*   vt   = (u16*)(smem + 51200);          // [64 s][72 d] bf16
  float* r3   = (float*)(smem + 60416);        // 192
  float* qc   = (float*)(smem + 61184);        // 256
  int*   idxA = (int*)(smem + 62208);          // 64
  float* sWp1 = (float*)(smem + 62464);        // 192
  float* sbp1 = (float*)(smem + 63232);        // 64
  float* sbp2 = (float*)(smem + 63488);        // 64
  float* sba1 = (float*)(smem + 63744);        // 256
  float* sba2 = (float*)(smem + 64768);        // 64

  const int t = threadIdx.x;
  const int w = t >> 6, l = t & 63, lq = l >> 4, ln = l & 15;
  const int d0 = 16*w + lq*4;

  if (t < 192) sWp1[t] = Wp1f[t];
  if (t < 64){ sbp1[t] = bp1f[t]; sbp2[t] = bp2[t]; sba2[t] = ba2[t]; }
  sba1[t] = ba1f[t];

  bfv8 Ape[2], A1[4][2], A2[8];
  #pragma unroll
  for (int kk = 0; kk < 2; ++kk)
    Ape[kk] = *(const bfv8*)(Wp2bf + (16*w + ln)*64 + kk*32 + lq*8);
  #pragma unroll
  for (int mt = 0; mt < 4; ++mt)
    #pragma unroll
    for (int kk = 0; kk < 2; ++kk)
      A1[mt][kk] = *(const bfv8*)(Wa1fbf + (64*w + mt*16 + ln)*64 + kk*32 + lq*8);
  #pragma unroll
  for (int kk = 0; kk < 8; ++kk)
    A2[kk] = *(const bfv8*)(Wa2bf + (16*w + ln)*256 + kk*32 + lq*8);
  __syncthreads();

  for (int ch = 0; ch < 2; ++ch) {
    const int p0 = blockIdx.x * 8 + ch * 4;
    const int b  = p0 >> 11;
    const int bN = b * 2048;
    // stage idx + q
    if (t < 64) idxA[t] = idxb[p0*16 + t];
    qc[t] = qT[(p0 + (t>>6))*64 + (t & 63)];
    __syncthreads();
    // pos_rel
    if (t < 192) { int c = t >> 6, s = t & 63; int n = (p0 + (s>>4)) & 2047;
      r3[c*64 + s] = pq[(b*3+c)*NN + n] - ps[(b*3+c)*MM + idxA[s]]; }
    __syncthreads();
    // pos hidden (relu(Wp1f . r + bp1f)) -> bf16 [s][i]
    { int s = t >> 2, iq = t & 3;
      float r0 = r3[s], r1 = r3[64+s], r2 = r3[128+s];
      u16 tmp[16];
      #pragma unroll
      for (int e = 0; e < 16; ++e) { int i = iq*16 + e;
        float v = sbp1[i] + sWp1[i*3]*r0 + sWp1[i*3+1]*r1 + sWp1[i*3+2]*r2;
        tmp[e] = f2bf(fmaxf(v, 0.f)); }
      *(bfv8*)&hp[s*72 + iq*16]     = *(const bfv8*)&tmp[0];
      *(bfv8*)&hp[s*72 + iq*16 + 8] = *(const bfv8*)&tmp[8];
    }
    __syncthreads();
    // pe = Wp2 @ hp (MFMA), then y = q - k_g + pe, val = v_g + pe
    {
      fv4 pe[4];
      #pragma unroll
      for (int nt = 0; nt < 4; ++nt) {
        fv4 acc = {0.f,0.f,0.f,0.f};
        #pragma unroll
        for (int kk = 0; kk < 2; ++kk) {
          bfv8 bb = *(const bfv8*)&hp[(nt*16 + ln)*72 + kk*32 + lq*8];
          acc = MFMA16(Ape[kk], bb, acc, 0, 0, 0);
        }
        pe[nt] = acc;
      }
      fv4 bp2q = *(const fv4*)&sbp2[d0];
      #pragma unroll
      for (int nt = 0; nt < 4; ++nt) {
        int s = nt*16 + ln;
        int mi = idxA[s];
        fv4 kg = *(const fv4*)(kT + (bN + mi)*64 + d0);
        fv4 vg = *(const fv4*)(vT + (bN + mi)*64 + d0);
        fv4 qv = *(const fv4*)&qc[nt*64 + d0];
        fv4 pv = pe[nt] + bp2q;
        fv4 yv = qv - kg + pv;
        fv4 vv = vg + pv;
        u16 yp[4], vp[4];
        #pragma unroll
        for (int r = 0; r < 4; ++r) { yp[r] = f2bf(yv[r]); vp[r] = f2bf(vv[r]); }
        *(bfv4*)&ylds[s*72 + d0] = *(const bfv4*)yp;
        *(bfv4*)&vt[s*72 + d0]   = *(const bfv4*)vp;
      }
    }
    __syncthreads();
    // GEMM1: a1 = Wa1f @ y, +ba1f, relu -> ha bf16 [s][h]
    #pragma unroll
    for (int nt = 0; nt < 4; ++nt) {
      int s = nt*16 + ln;
      bfv8 b0 = *(const bfv8*)&ylds[s*72 + lq*8];
      bfv8 b1 = *(const bfv8*)&ylds[s*72 + 32 + lq*8];
      #pragma unroll
      for (int mt = 0; mt < 4; ++mt) {
        fv4 acc = {0.f,0.f,0.f,0.f};
        acc = MFMA16(A1[mt][0], b0, acc, 0, 0, 0);
        acc = MFMA16(A1[mt][1], b1, acc, 0, 0, 0);
        int h0 = 64*w + mt*16 + lq*4;
        fv4 bq = *(const fv4*)&sba1[h0];
        u16 hv[4];
        #pragma unroll
        for (int r = 0; r < 4; ++r) hv[r] = f2bf(fmaxf(acc[r] + bq[r], 0.f));
        *(bfv4*)&ha[s*264 + h0] = *(const bfv4*)hv;
      }
    }
    __syncthreads();
    // GEMM2: a2 = Wa2 @ ha, +ba2 -> at f32 [s][d]
    {
      fv4 acc2[4];
      #pragma unroll
      for (int nt = 0; nt < 4; ++nt) acc2[nt] = (fv4){0.f,0.f,0.f,0.f};
      #pragma unroll
      for (int kk = 0; kk < 8; ++kk) {
        #pragma unroll
        for (int nt = 0; nt < 4; ++nt) {
          bfv8 bb = *(const bfv8*)&ha[(nt*16 + ln)*264 + kk*32 + lq*8];
          acc2[nt] = MFMA16(A2[kk], bb, acc2[nt], 0, 0, 0);
        }
      }
      fv4 ba2q = *(const fv4*)&sba2[d0];
      #pragma unroll
      for (int nt = 0; nt < 4; ++nt) {
        int s = nt*16 + ln;
        fv4 o = acc2[nt] + ba2q;
        *(fv4*)&at[s*68 + d0] = o;
      }
    }
    __syncthreads();
    // softmax over K + weighted val sum
    {
      int dd = t & 63, pt = t >> 6;
      float a[16];
      #pragma unroll
      for (int k = 0; k < 16; ++k) a[k] = at[(pt*16 + k)*68 + dd];
      float mx = a[0];
      #pragma unroll
      for (int k = 1; k < 16; ++k) mx = fmaxf(mx, a[k]);
      float sum = 0.f, num = 0.f;
      #pragma unroll
      for (int k = 0; k < 16; ++k) {
        float e = __expf(a[k] - mx);
        sum += e;
        num += e * bf2f(vt[(pt*16 + k)*72 + dd]);
      }
      aggT[(p0 + pt)*64 + dd] = num / sum;
    }
    __syncthreads();
  }
}

// ---------------------------------------------------------------------------
// epilogue: out[b,c,n] = We[c,:]·agg[b,:,n] + be[c] + fq[b,c,n]
// ---------------------------------------------------------------------------
__global__ __launch_bounds__(256) void k_epilogue(
    const float* __restrict__ aggT, const float* __restrict__ We,
    const float* __restrict__ be, const float* __restrict__ fq, float* __restrict__ out) {
  int bid = blockIdx.x;               // 4 * 32 * 32 = 4096
  int b  = bid >> 10;
  int c0 = ((bid >> 5) & 31) * 4;
  int n0 = (bid & 31) * 64;
  int t = threadIdx.x;
  int n = n0 + (t & 63), c = c0 + (t >> 6);
  float acc = be[c];
  const float* ag = aggT + (b * NN + n) * 64;
  const float* wr = We + c * 64;
  #pragma unroll 8
  for (int dd = 0; dd < 64; ++dd) acc = fmaf(wr[dd], ag[dd], acc);
  int o = (b * 128 + c) * NN + n;
  out[o] = acc + fq[o];
}

// ---------------------------------------------------------------------------
extern "C" void kernel_launch(void* const* d_in, const int* in_sizes, int n_in,
                              void* d_out, int out_size, void* d_ws, size_t ws_size,
                              hipStream_t stream) {
  (void)in_sizes; (void)n_in; (void)out_size; (void)ws_size;
  const float* pq  = (const float*)d_in[0];
  const float* fq  = (const float*)d_in[1];
  const float* ps  = (const float*)d_in[2];
  const float* fs  = (const float*)d_in[3];
  const float* Wq  = (const float*)d_in[4];  const float* bq  = (const float*)d_in[5];
  const float* Wk  = (const float*)d_in[6];  const float* bk  = (const float*)d_in[7];
  const float* Wv  = (const float*)d_in[8];  const float* bv  = (const float*)d_in[9];
  const float* Wp1 = (const float*)d_in[10]; const float* bp1 = (const float*)d_in[11];
  const float* gp  = (const float*)d_in[12]; const float* btp = (const float*)d_in[13];
  const float* Wp2 = (const float*)d_in[14]; const float* bp2 = (const float*)d_in[15];
  const float* Wa1 = (const float*)d_in[16]; const float* ba1 = (const float*)d_in[17];
  const float* ga  = (const float*)d_in[18]; const float* bta = (const float*)d_in[19];
  const float* Wa2 = (const float*)d_in[20]; const float* ba2 = (const float*)d_in[21];
  const float* We  = (const float*)d_in[22]; const float* be  = (const float*)d_in[23];
  float* ws = (float*)d_ws;
  float* qT    = ws;
  float* kT    = ws + 524288;
  float* vT    = ws + 1048576;
  float* aggT  = ws + 1572864;
  int*   idxb  = (int*)(ws + 2097152);
  float* Wqt   = ws + 2228224;
  float* Wkt   = ws + 2236416;
  float* Wvt   = ws + 2244608;
  float* Wp1f  = ws + 2252800;
  float* bp1f  = ws + 2252992;
  float* ba1f  = ws + 2253056;
  float* stat  = ws + 2253312;
  float* G     = ws + 2253376;
  float* ySum  = ws + 2257472;
  float* ySumP = ws + 2257536;
  u16*   Wp2bf  = (u16*)(ws + 2273920);
  u16*   Wa2bf  = (u16*)(ws + 2275968);
  u16*   Wa1fbf = (u16*)(ws + 2284160);
  float* Gpart = (float*)d_out;   // 256*4096 = 1M floats: d_out used as scratch,
                                  // fully overwritten by k_epilogue afterwards
  float* out   = (float*)d_out;

  k_prep<<<64, 256, 0, stream>>>(Wq, Wk, Wv, Wp2, Wa2, Wqt, Wkt, Wvt, Wp2bf, Wa2bf, stat);
  k_qkv<<<3072, 256, 0, stream>>>(fq, fs, Wqt, Wkt, Wvt, bq, bk, bv, qT, kT, vT);
  k_knn<<<2048, 256, 0, stream>>>(pq, ps, idxb);
  k_posstats<<<512, 256, 0, stream>>>(pq, ps, idxb, stat);
  k_posfinal<<<1, 64, 0, stream>>>(Wp1, bp1, gp, btp, stat, Wp1f, bp1f);
  k_ystats<<<256, 256, 0, stream>>>(pq, ps, qT, kT, idxb, Wp1f, bp1f, Wp2bf, bp2,
                                    Gpart, ySumP);
  k_gred<<<17, 256, 0, stream>>>(Gpart, ySumP, G, ySum);
  k_attnfinal<<<256, 256, 0, stream>>>(Wa1, ba1, ga, bta, ySum, G, Wa1fbf, ba1f);
  k_main<<<1024, 256, 0, stream>>>(pq, ps, qT, kT, vT, idxb, Wp1f, bp1f, Wp2bf, bp2,
                                   Wa1fbf, ba1f, Wa2bf, ba2, aggT);
  k_epilogue<<<4096, 256, 0, stream>>>(aggT, We, be, fq, out);
}

// Round 3
// 352.249 us; speedup vs baseline: 3.9417x; 1.6438x over previous
//
#include <hip/hip_runtime.h>
#include <stdint.h>

#define NN 2048
#define MM 2048
#define NSAMP 131072   // B*N*K

typedef float  fv4 __attribute__((ext_vector_type(4)));
typedef short  bfv8 __attribute__((ext_vector_type(8)));
typedef short  bfv4 __attribute__((ext_vector_type(4)));
typedef unsigned short u16;

__device__ inline u16 f2bf(float x){
  unsigned u = __float_as_uint(x);
  return (u16)((u + 0x7FFFu + ((u>>16)&1u)) >> 16);
}
__device__ inline float bf2f(u16 u){ return __uint_as_float(((unsigned)u)<<16); }
#define MFMA16 __builtin_amdgcn_mfma_f32_16x16x32_bf16

// ---------------------------------------------------------------------------
// prep: transpose qkv weights + bf16-pack Wp2 (row-major d,i) and Wa2 (d,h)
// ---------------------------------------------------------------------------
__global__ __launch_bounds__(256) void k_prep(
    const float* __restrict__ Wq, const float* __restrict__ Wk, const float* __restrict__ Wv,
    const float* __restrict__ Wp2, const float* __restrict__ Wa2,
    float* __restrict__ Wqt, float* __restrict__ Wkt, float* __restrict__ Wvt,
    u16* __restrict__ Wp2bf, u16* __restrict__ Wa2bf) {
  int gid = blockIdx.x * 256 + threadIdx.x;   // grid 64*256 = 16384
  if (gid < 8192)  { int c = gid >> 6, d = gid & 63;
    Wqt[gid] = Wq[d*128 + c]; Wkt[gid] = Wk[d*128 + c]; Wvt[gid] = Wv[d*128 + c]; }
  if (gid < 4096)  Wp2bf[gid] = f2bf(Wp2[gid]);     // (D,D) row-major
  if (gid < 16384) Wa2bf[gid] = f2bf(Wa2[gid]);     // (D,H) row-major
}

// ---------------------------------------------------------------------------
// q/k/v 1x1 conv -> n-major (point,d) layout
// ---------------------------------------------------------------------------
__global__ __launch_bounds__(256) void k_qkv(
    const float* __restrict__ fq, const float* __restrict__ fs,
    const float* __restrict__ Wqt, const float* __restrict__ Wkt, const float* __restrict__ Wvt,
    const float* __restrict__ bq, const float* __restrict__ bk, const float* __restrict__ bv,
    float* __restrict__ qT, float* __restrict__ kT, float* __restrict__ vT) {
  int bid = blockIdx.x;              // 3 * 4 * 256 = 3072
  int mat = bid >> 10;
  int rem = bid & 1023;
  int b  = rem >> 8;
  int n0 = (rem & 255) * 8;
  int t = threadIdx.x, d = t & 63, pc = t >> 6;
  const float* W   = mat == 0 ? Wqt : (mat == 1 ? Wkt : Wvt);
  const float* src = mat == 0 ? fq  : fs;
  const float* bia = mat == 0 ? bq  : (mat == 1 ? bk : bv);
  float* dst = mat == 0 ? qT : (mat == 1 ? kT : vT);
  int n_a = n0 + pc, n_b = n0 + 4 + pc;
  const float* sa = src + b * 128 * NN;
  float acc0 = bia[d], acc1 = acc0;
  #pragma unroll 8
  for (int c = 0; c < 128; ++c) {
    float w = W[c * 64 + d];
    acc0 = fmaf(w, sa[c * NN + n_a], acc0);
    acc1 = fmaf(w, sa[c * NN + n_b], acc1);
  }
  dst[(b * NN + n_a) * 64 + d] = acc0;
  dst[(b * NN + n_b) * 64 + d] = acc1;
}

// ---------------------------------------------------------------------------
// KNN: one wave per query
// ---------------------------------------------------------------------------
__global__ __launch_bounds__(256) void k_knn(
    const float* __restrict__ pq, const float* __restrict__ ps, int* __restrict__ idxb) {
  __shared__ unsigned long long cand[4][64 * 16];
  int t = threadIdx.x, w = t >> 6, lane = t & 63;
  int qi = blockIdx.x * 4 + w;       // 0..8191
  int b = qi >> 11, n = qi & 2047;
  const float* pqb = pq + b * 3 * NN;
  const float* psb = ps + b * 3 * MM;
  float qx = pqb[n], qy = pqb[NN + n], qz = pqb[2 * NN + n];
  float qq = qx * qx + qy * qy + qz * qz;
  unsigned long long list[16];
  #pragma unroll
  for (int i = 0; i < 16; ++i) list[i] = ~0ULL;
  for (int m = lane; m < MM; m += 64) {
    float sx = psb[m], sy = psb[MM + m], sz = psb[2 * MM + m];
    float ss  = sx * sx + sy * sy + sz * sz;
    float dot = qx * sx + qy * sy + qz * sz;
    float d2  = qq + ss - 2.f * dot;
    unsigned int bu = __float_as_uint(d2);
    bu = (bu & 0x80000000u) ? ~bu : (bu | 0x80000000u);
    unsigned long long pk = (((unsigned long long)bu) << 32) | (unsigned int)m;
    if (pk < list[15]) {
      list[15] = pk;
      #pragma unroll
      for (int j = 15; j > 0; --j) {
        unsigned long long a = list[j - 1], c = list[j];
        list[j - 1] = c < a ? c : a;
        list[j]     = c < a ? a : c;
      }
    }
  }
  #pragma unroll
  for (int i = 0; i < 16; ++i) cand[w][lane * 16 + i] = list[i];
  int head = 0;
  for (int r = 0; r < 16; ++r) {
    unsigned long long v = (head < 16) ? cand[w][lane * 16 + head] : ~0ULL;
    unsigned long long mv = v;
    #pragma unroll
    for (int off = 32; off > 0; off >>= 1) {
      unsigned long long o = __shfl_xor(mv, off, 64);
      mv = o < mv ? o : mv;
    }
    if (v == mv) head++;
    if (lane == 0) idxb[qi * 16 + r] = (int)(mv & 0xFFFFFFFFu);
  }
}

// ---------------------------------------------------------------------------
// pos_rel first/second moments -> per-block partials (NO atomics)
// ---------------------------------------------------------------------------
__global__ __launch_bounds__(256) void k_posstats(
    const float* __restrict__ pq, const float* __restrict__ ps,
    const int* __restrict__ idxb, float* __restrict__ posPart) {
  __shared__ float red[4][9];
  int t = threadIdx.x;
  int gid = blockIdx.x * 256 + t;   // 131072
  int b = gid >> 15;
  int n = (gid >> 4) & 2047;
  int mi = idxb[gid];
  const float* pqb = pq + b * 3 * NN;
  const float* psb = ps + b * 3 * MM;
  float r0 = pqb[n]          - psb[mi];
  float r1 = pqb[NN + n]     - psb[MM + mi];
  float r2 = pqb[2 * NN + n] - psb[2 * MM + mi];
  float vals[9] = {r0, r1, r2, r0*r0, r0*r1, r0*r2, r1*r1, r1*r2, r2*r2};
  #pragma unroll
  for (int i = 0; i < 9; ++i) {
    float v = vals[i];
    #pragma unroll
    for (int off = 32; off > 0; off >>= 1) v += __shfl_xor(v, off, 64);
    if ((t & 63) == 0) red[t >> 6][i] = v;
  }
  __syncthreads();
  if (t < 9) posPart[blockIdx.x * 12 + t] =
      red[0][t] + red[1][t] + red[2][t] + red[3][t];
}

// ---------------------------------------------------------------------------
// reduce pos partials + fold pos-BN into Wp1/bp1 (exact)
// ---------------------------------------------------------------------------
__global__ __launch_bounds__(256) void k_posfinal(
    const float* __restrict__ Wp1, const float* __restrict__ bp1,
    const float* __restrict__ gp, const float* __restrict__ btp,
    const float* __restrict__ posPart, float* __restrict__ Wp1f, float* __restrict__ bp1f) {
  __shared__ float part[144];
  __shared__ float st[9];
  int t = threadIdx.x;
  if (t < 144) { int i = t >> 4, c = t & 15;
    float s = 0.f;
    for (int bb = c; bb < 512; bb += 16) s += posPart[bb * 12 + i];
    part[i * 16 + c] = s;
  }
  __syncthreads();
  if (t < 9) { float s = 0.f;
    #pragma unroll
    for (int c = 0; c < 16; ++c) s += part[t * 16 + c];
    st[t] = s;
  }
  __syncthreads();
  if (t < 64) {
    int d = t;
    const float invN = 1.f / (float)NSAMP;
    float m0 = st[0]*invN, m1 = st[1]*invN, m2 = st[2]*invN;
    float C00 = st[3]*invN - m0*m0, C01 = st[4]*invN - m0*m1, C02 = st[5]*invN - m0*m2;
    float C11 = st[6]*invN - m1*m1, C12 = st[7]*invN - m1*m2, C22 = st[8]*invN - m2*m2;
    float w0 = Wp1[d*3], w1 = Wp1[d*3+1], w2 = Wp1[d*3+2];
    float mean = w0*m0 + w1*m1 + w2*m2 + bp1[d];
    float var = w0*w0*C00 + w1*w1*C11 + w2*w2*C22 + 2.f*(w0*w1*C01 + w0*w2*C02 + w1*w2*C12);
    float scale = gp[d] * rsqrtf(var + 1e-5f);
    Wp1f[d*3]   = scale * w0;
    Wp1f[d*3+1] = scale * w1;
    Wp1f[d*3+2] = scale * w2;
    bp1f[d] = btp[d] + scale * (bp1[d] - mean);
  }
}

// ---------------------------------------------------------------------------
// y-stats: per-block Gram via MFMA (Y Y^T), partials to Gpart (= d_out scratch)
// ---------------------------------------------------------------------------
__global__ __launch_bounds__(256) void k_ystats(
    const float* __restrict__ pq, const float* __restrict__ ps,
    const float* __restrict__ qT, const float* __restrict__ kT,
    const int* __restrict__ idxb,
    const float* __restrict__ Wp1f, const float* __restrict__ bp1f,
    const u16* __restrict__ Wp2bf, const float* __restrict__ bp2,
    float* __restrict__ Gpart, float* __restrict__ ySumPart) {
  __shared__ __align__(16) unsigned char smem[21760];
  u16*   hp   = (u16*)smem;                 // [64 s][72 i] bf16
  u16*   y2   = (u16*)(smem + 9216);        // [64 d][72 s] bf16
  float* r3   = (float*)(smem + 18432);     // 192
  float* qc   = (float*)(smem + 19200);     // 256
  int*   idxA = (int*)(smem + 20224);       // 64
  float* sWp1 = (float*)(smem + 20480);     // 192
  float* sbp1 = (float*)(smem + 21248);     // 64
  float* sbp2 = (float*)(smem + 21504);     // 64

  const int t = threadIdx.x;
  const int w = t >> 6, l = t & 63, lq = l >> 4, ln = l & 15;
  const int d0 = 16*w + lq*4;

  if (t < 192) sWp1[t] = Wp1f[t];
  if (t < 64){ sbp1[t] = bp1f[t]; sbp2[t] = bp2[t]; }

  bfv8 Ape[2];
  #pragma unroll
  for (int kk = 0; kk < 2; ++kk)
    Ape[kk] = *(const bfv8*)(Wp2bf + (16*w + ln)*64 + kk*32 + lq*8);

  fv4 gacc[4];
  #pragma unroll
  for (int nt = 0; nt < 4; ++nt) gacc[nt] = (fv4){0.f,0.f,0.f,0.f};
  float ysacc = 0.f;
  __syncthreads();

  for (int ch = 0; ch < 8; ++ch) {
    const int p0 = blockIdx.x * 32 + ch * 4;
    const int b  = p0 >> 11;
    const int bN = b * 2048;
    if (t < 64) idxA[t] = idxb[p0*16 + t];
    qc[t] = qT[(p0 + (t>>6))*64 + (t & 63)];
    __syncthreads();
    if (t < 192) { int c = t >> 6, s = t & 63; int n = (p0 + (s>>4)) & 2047;
      r3[c*64 + s] = pq[(b*3+c)*NN + n] - ps[(b*3+c)*MM + idxA[s]]; }
    __syncthreads();
    { int s = t >> 2, iq = t & 3;
      float r0 = r3[s], r1 = r3[64+s], r2 = r3[128+s];
      u16 tmp[16];
      #pragma unroll
      for (int e = 0; e < 16; ++e) { int i = iq*16 + e;
        float v = sbp1[i] + sWp1[i*3]*r0 + sWp1[i*3+1]*r1 + sWp1[i*3+2]*r2;
        tmp[e] = f2bf(fmaxf(v, 0.f)); }
      *(bfv8*)&hp[s*72 + iq*16]     = *(const bfv8*)&tmp[0];
      *(bfv8*)&hp[s*72 + iq*16 + 8] = *(const bfv8*)&tmp[8];
    }
    __syncthreads();
    {
      fv4 pe[4];
      #pragma unroll
      for (int nt = 0; nt < 4; ++nt) {
        fv4 acc = {0.f,0.f,0.f,0.f};
        #pragma unroll
        for (int kk = 0; kk < 2; ++kk) {
          bfv8 bb = *(const bfv8*)&hp[(nt*16 + ln)*72 + kk*32 + lq*8];
          acc = MFMA16(Ape[kk], bb, acc, 0, 0, 0);
        }
        pe[nt] = acc;
      }
      fv4 bp2q = *(const fv4*)&sbp2[d0];
      #pragma unroll
      for (int nt = 0; nt < 4; ++nt) {
        int s = nt*16 + ln;
        int mi = idxA[s];
        fv4 kg = *(const fv4*)(kT + (bN + mi)*64 + d0);
        fv4 qv = *(const fv4*)&qc[nt*64 + d0];
        fv4 yv = qv - kg + pe[nt] + bp2q;
        #pragma unroll
        for (int r = 0; r < 4; ++r) y2[(d0 + r)*72 + s] = f2bf(yv[r]);
      }
    }
    __syncthreads();
    // Gram: G += Y Y^T  (wave w owns rows [16w,16w+16))
    #pragma unroll
    for (int kk = 0; kk < 2; ++kk) {
      bfv8 aa = *(const bfv8*)&y2[(16*w + ln)*72 + kk*32 + lq*8];
      #pragma unroll
      for (int nt = 0; nt < 4; ++nt) {
        bfv8 bb = *(const bfv8*)&y2[(nt*16 + ln)*72 + kk*32 + lq*8];
        gacc[nt] = MFMA16(aa, bb, gacc[nt], 0, 0, 0);
      }
    }
    if (t < 64) {
      float s = 0.f;
      #pragma unroll
      for (int ss = 0; ss < 64; ++ss) s += bf2f(y2[t*72 + ss]);
      ysacc += s;
    }
    __syncthreads();
  }
  #pragma unroll
  for (int nt = 0; nt < 4; ++nt)
    #pragma unroll
    for (int r = 0; r < 4; ++r)
      Gpart[blockIdx.x*4096 + (16*w + lq*4 + r)*64 + nt*16 + ln] = gacc[nt][r];
  if (t < 64) ySumPart[blockIdx.x*64 + t] = ysacc;
}

// ---------------------------------------------------------------------------
// reduce Gram / ySum partials (no atomics anywhere)
// ---------------------------------------------------------------------------
__global__ __launch_bounds__(256) void k_gred(
    const float* __restrict__ Gpart, const float* __restrict__ ySumPart,
    float* __restrict__ G, float* __restrict__ ySum) {
  int bid = blockIdx.x, t = threadIdx.x;   // grid 17
  if (bid < 16) {
    int j = bid*256 + t;
    float s = 0.f;
    for (int p = 0; p < 256; ++p) s += Gpart[p*4096 + j];
    G[j] = s;
  } else if (t < 64) {
    float s = 0.f;
    for (int p = 0; p < 256; ++p) s += ySumPart[p*64 + t];
    ySum[t] = s;
  }
}

// ---------------------------------------------------------------------------
// fold attn-BN into Wa1/ba1; emit bf16 Wa1f
// ---------------------------------------------------------------------------
__global__ __launch_bounds__(256) void k_attnfinal(
    const float* __restrict__ Wa1, const float* __restrict__ ba1,
    const float* __restrict__ ga, const float* __restrict__ bta,
    const float* __restrict__ ySum, const float* __restrict__ G,
    u16* __restrict__ Wa1fbf, float* __restrict__ ba1f) {
  __shared__ float red[256];
  __shared__ float mu[64];
  __shared__ float sc[1];
  int h = blockIdx.x, t = threadIdx.x;
  const float invN = 1.f / (float)NSAMP;
  if (t < 64) mu[t] = ySum[t] * invN;
  __syncthreads();
  float acc = 0.f;
  #pragma unroll
  for (int e = 0; e < 16; ++e) {
    int pi = t*16 + e, i = pi >> 6, j = pi & 63;
    float cov = G[pi]*invN - mu[i]*mu[j];
    acc += Wa1[h*64 + i] * Wa1[h*64 + j] * cov;
  }
  red[t] = acc;
  __syncthreads();
  for (int s = 128; s > 0; s >>= 1) { if (t < s) red[t] += red[t + s]; __syncthreads(); }
  float var = red[0];
  __syncthreads();
  red[t] = (t < 64) ? Wa1[h*64 + t] * mu[t] : 0.f;
  __syncthreads();
  for (int s = 128; s > 0; s >>= 1) { if (t < s) red[t] += red[t + s]; __syncthreads(); }
  if (t == 0) {
    float mean  = red[0] + ba1[h];
    float scale = ga[h] * rsqrtf(var + 1e-5f);
    sc[0] = scale;
    ba1f[h] = bta[h] + scale * (ba1[h] - mean);
  }
  __syncthreads();
  if (t < 64) Wa1fbf[h*64 + t] = f2bf(sc[0] * Wa1[h*64 + t]);
}

// ---------------------------------------------------------------------------
// main fused kernel (MFMA)
// ---------------------------------------------------------------------------
__global__ __launch_bounds__(256) void k_main(
    const float* __restrict__ pq, const float* __restrict__ ps,
    const float* __restrict__ qT, const float* __restrict__ kT, const float* __restrict__ vT,
    const int* __restrict__ idxb,
    const float* __restrict__ Wp1f, const float* __restrict__ bp1f,
    const u16* __restrict__ Wp2bf, const float* __restrict__ bp2,
    const u16* __restrict__ Wa1fbf, const float* __restrict__ ba1f,
    const u16* __restrict__ Wa2bf, const float* __restrict__ ba2,
    float* __restrict__ aggT) {
  __shared__ __align__(16) unsigned char smem[65024];
  u16*   hp   = (u16*)smem;                    // [64 s][72 i] bf16 (aliases ha)
  u16*   ha   = (u16*)smem;                    // [64 s][264 h] bf16
  u16*   ylds = (u16*)(smem + 33792);          // [64 s][72 d] bf16 (aliases at)
  float* at   = (float*)(smem + 33792);        // [64 s][68 d] f32
  u16*   vt   = (u16*)(smem + 51200);          // [64 s][72 d] bf16
  float* r3   = (float*)(smem + 60416);        // 192
  float* qc   = (float*)(smem + 61184);        // 256
  int*   idxA = (int*)(smem + 62208);          // 64
  float* sWp1 = (float*)(smem + 62464);        // 192
  float* sbp1 = (float*)(smem + 63232);        // 64
  float* sbp2 = (float*)(smem + 63488);        // 64
  float* sba1 = (float*)(smem + 63744);        // 256
  float* sba2 = (float*)(smem + 64768);        // 64

  const int t = threadIdx.x;
  const int w = t >> 6, l = t & 63, lq = l >> 4, ln = l & 15;
  const int d0 = 16*w + lq*4;

  if (t < 192) sWp1[t] = Wp1f[t];
  if (t < 64){ sbp1[t] = bp1f[t]; sbp2[t] = bp2[t]; sba2[t] = ba2[t]; }
  sba1[t] = ba1f[t];

  bfv8 Ape[2], A1[4][2], A2[8];
  #pragma unroll
  for (int kk = 0; kk < 2; ++kk)
    Ape[kk] = *(const bfv8*)(Wp2bf + (16*w + ln)*64 + kk*32 + lq*8);
  #pragma unroll
  for (int mt = 0; mt < 4; ++mt)
    #pragma unroll
    for (int kk = 0; kk < 2; ++kk)
      A1[mt][kk] = *(const bfv8*)(Wa1fbf + (64*w + mt*16 + ln)*64 + kk*32 + lq*8);
  #pragma unroll
  for (int kk = 0; kk < 8; ++kk)
    A2[kk] = *(const bfv8*)(Wa2bf + (16*w + ln)*256 + kk*32 + lq*8);
  __syncthreads();

  for (int ch = 0; ch < 2; ++ch) {
    const int p0 = blockIdx.x * 8 + ch * 4;
    const int b  = p0 >> 11;
    const int bN = b * 2048;
    if (t < 64) idxA[t] = idxb[p0*16 + t];
    qc[t] = qT[(p0 + (t>>6))*64 + (t & 63)];
    __syncthreads();
    if (t < 192) { int c = t >> 6, s = t & 63; int n = (p0 + (s>>4)) & 2047;
      r3[c*64 + s] = pq[(b*3+c)*NN + n] - ps[(b*3+c)*MM + idxA[s]]; }
    __syncthreads();
    { int s = t >> 2, iq = t & 3;
      float r0 = r3[s], r1 = r3[64+s], r2 = r3[128+s];
      u16 tmp[16];
      #pragma unroll
      for (int e = 0; e < 16; ++e) { int i = iq*16 + e;
        float v = sbp1[i] + sWp1[i*3]*r0 + sWp1[i*3+1]*r1 + sWp1[i*3+2]*r2;
        tmp[e] = f2bf(fmaxf(v, 0.f)); }
      *(bfv8*)&hp[s*72 + iq*16]     = *(const bfv8*)&tmp[0];
      *(bfv8*)&hp[s*72 + iq*16 + 8] = *(const bfv8*)&tmp[8];
    }
    __syncthreads();
    {
      fv4 pe[4];
      #pragma unroll
      for (int nt = 0; nt < 4; ++nt) {
        fv4 acc = {0.f,0.f,0.f,0.f};
        #pragma unroll
        for (int kk = 0; kk < 2; ++kk) {
          bfv8 bb = *(const bfv8*)&hp[(nt*16 + ln)*72 + kk*32 + lq*8];
          acc = MFMA16(Ape[kk], bb, acc, 0, 0, 0);
        }
        pe[nt] = acc;
      }
      fv4 bp2q = *(const fv4*)&sbp2[d0];
      #pragma unroll
      for (int nt = 0; nt < 4; ++nt) {
        int s = nt*16 + ln;
        int mi = idxA[s];
        fv4 kg = *(const fv4*)(kT + (bN + mi)*64 + d0);
        fv4 vg = *(const fv4*)(vT + (bN + mi)*64 + d0);
        fv4 qv = *(const fv4*)&qc[nt*64 + d0];
        fv4 pv = pe[nt] + bp2q;
        fv4 yv = qv - kg + pv;
        fv4 vv = vg + pv;
        u16 yp[4], vp[4];
        #pragma unroll
        for (int r = 0; r < 4; ++r) { yp[r] = f2bf(yv[r]); vp[r] = f2bf(vv[r]); }
        *(bfv4*)&ylds[s*72 + d0] = *(const bfv4*)yp;
        *(bfv4*)&vt[s*72 + d0]   = *(const bfv4*)vp;
      }
    }
    __syncthreads();
    // GEMM1: a1 = Wa1f @ y, +ba1f, relu -> ha bf16 [s][h]
    #pragma unroll
    for (int nt = 0; nt < 4; ++nt) {
      int s = nt*16 + ln;
      bfv8 b0 = *(const bfv8*)&ylds[s*72 + lq*8];
      bfv8 b1 = *(const bfv8*)&ylds[s*72 + 32 + lq*8];
      #pragma unroll
      for (int mt = 0; mt < 4; ++mt) {
        fv4 acc = {0.f,0.f,0.f,0.f};
        acc = MFMA16(A1[mt][0], b0, acc, 0, 0, 0);
        acc = MFMA16(A1[mt][1], b1, acc, 0, 0, 0);
        int h0 = 64*w + mt*16 + lq*4;
        fv4 bq = *(const fv4*)&sba1[h0];
        u16 hv[4];
        #pragma unroll
        for (int r = 0; r < 4; ++r) hv[r] = f2bf(fmaxf(acc[r] + bq[r], 0.f));
        *(bfv4*)&ha[s*264 + h0] = *(const bfv4*)hv;
      }
    }
    __syncthreads();
    // GEMM2: a2 = Wa2 @ ha, +ba2 -> at f32 [s][d]
    {
      fv4 acc2[4];
      #pragma unroll
      for (int nt = 0; nt < 4; ++nt) acc2[nt] = (fv4){0.f,0.f,0.f,0.f};
      #pragma unroll
      for (int kk = 0; kk < 8; ++kk) {
        #pragma unroll
        for (int nt = 0; nt < 4; ++nt) {
          bfv8 bb = *(const bfv8*)&ha[(nt*16 + ln)*264 + kk*32 + lq*8];
          acc2[nt] = MFMA16(A2[kk], bb, acc2[nt], 0, 0, 0);
        }
      }
      fv4 ba2q = *(const fv4*)&sba2[d0];
      #pragma unroll
      for (int nt = 0; nt < 4; ++nt) {
        int s = nt*16 + ln;
        fv4 o = acc2[nt] + ba2q;
        *(fv4*)&at[s*68 + d0] = o;
      }
    }
    __syncthreads();
    // softmax over K + weighted val sum
    {
      int dd = t & 63, pt = t >> 6;
      float a[16];
      #pragma unroll
      for (int k = 0; k < 16; ++k) a[k] = at[(pt*16 + k)*68 + dd];
      float mx = a[0];
      #pragma unroll
      for (int k = 1; k < 16; ++k) mx = fmaxf(mx, a[k]);
      float sum = 0.f, num = 0.f;
      #pragma unroll
      for (int k = 0; k < 16; ++k) {
        float e = __expf(a[k] - mx);
        sum += e;
        num += e * bf2f(vt[(pt*16 + k)*72 + dd]);
      }
      aggT[(p0 + pt)*64 + dd] = num / sum;
    }
    __syncthreads();
  }
}

// ---------------------------------------------------------------------------
// epilogue: out[b,c,n] = We[c,:]·agg[b,:,n] + be[c] + fq[b,c,n]
// ---------------------------------------------------------------------------
__global__ __launch_bounds__(256) void k_epilogue(
    const float* __restrict__ aggT, const float* __restrict__ We,
    const float* __restrict__ be, const float* __restrict__ fq, float* __restrict__ out) {
  int bid = blockIdx.x;               // 4 * 32 * 32 = 4096
  int b  = bid >> 10;
  int c0 = ((bid >> 5) & 31) * 4;
  int n0 = (bid & 31) * 64;
  int t = threadIdx.x;
  int n = n0 + (t & 63), c = c0 + (t >> 6);
  float acc = be[c];
  const float* ag = aggT + (b * NN + n) * 64;
  const float* wr = We + c * 64;
  #pragma unroll 8
  for (int dd = 0; dd < 64; ++dd) acc = fmaf(wr[dd], ag[dd], acc);
  int o = (b * 128 + c) * NN + n;
  out[o] = acc + fq[o];
}

// ---------------------------------------------------------------------------
extern "C" void kernel_launch(void* const* d_in, const int* in_sizes, int n_in,
                              void* d_out, int out_size, void* d_ws, size_t ws_size,
                              hipStream_t stream) {
  (void)in_sizes; (void)n_in; (void)out_size; (void)ws_size;
  const float* pq  = (const float*)d_in[0];
  const float* fq  = (const float*)d_in[1];
  const float* ps  = (const float*)d_in[2];
  const float* fs  = (const float*)d_in[3];
  const float* Wq  = (const float*)d_in[4];  const float* bq  = (const float*)d_in[5];
  const float* Wk  = (const float*)d_in[6];  const float* bk  = (const float*)d_in[7];
  const float* Wv  = (const float*)d_in[8];  const float* bv  = (const float*)d_in[9];
  const float* Wp1 = (const float*)d_in[10]; const float* bp1 = (const float*)d_in[11];
  const float* gp  = (const float*)d_in[12]; const float* btp = (const float*)d_in[13];
  const float* Wp2 = (const float*)d_in[14]; const float* bp2 = (const float*)d_in[15];
  const float* Wa1 = (const float*)d_in[16]; const float* ba1 = (const float*)d_in[17];
  const float* ga  = (const float*)d_in[18]; const float* bta = (const float*)d_in[19];
  const float* Wa2 = (const float*)d_in[20]; const float* ba2 = (const float*)d_in[21];
  const float* We  = (const float*)d_in[22]; const float* be  = (const float*)d_in[23];
  float* ws = (float*)d_ws;
  float* qT    = ws;
  float* kT    = ws + 524288;
  float* vT    = ws + 1048576;
  float* aggT  = ws + 1572864;
  int*   idxb  = (int*)(ws + 2097152);
  float* Wqt   = ws + 2228224;
  float* Wkt   = ws + 2236416;
  float* Wvt   = ws + 2244608;
  float* Wp1f  = ws + 2252800;
  float* bp1f  = ws + 2252992;
  float* ba1f  = ws + 2253056;
  float* G     = ws + 2253376;
  float* ySum  = ws + 2257472;
  float* ySumP = ws + 2257536;
  u16*   Wp2bf  = (u16*)(ws + 2273920);
  u16*   Wa2bf  = (u16*)(ws + 2275968);
  u16*   Wa1fbf = (u16*)(ws + 2284160);
  // d_out doubles as scratch: posPart (512*12 floats) then Gpart (256*4096
  // floats). Both fully consumed before k_epilogue overwrites d_out.
  float* posPart = (float*)d_out;
  float* Gpart   = (float*)d_out;
  float* out     = (float*)d_out;

  k_prep<<<64, 256, 0, stream>>>(Wq, Wk, Wv, Wp2, Wa2, Wqt, Wkt, Wvt, Wp2bf, Wa2bf);
  k_qkv<<<3072, 256, 0, stream>>>(fq, fs, Wqt, Wkt, Wvt, bq, bk, bv, qT, kT, vT);
  k_knn<<<2048, 256, 0, stream>>>(pq, ps, idxb);
  k_posstats<<<512, 256, 0, stream>>>(pq, ps, idxb, posPart);
  k_posfinal<<<1, 256, 0, stream>>>(Wp1, bp1, gp, btp, posPart, Wp1f, bp1f);
  k_ystats<<<256, 256, 0, stream>>>(pq, ps, qT, kT, idxb, Wp1f, bp1f, Wp2bf, bp2,
                                    Gpart, ySumP);
  k_gred<<<17, 256, 0, stream>>>(Gpart, ySumP, G, ySum);
  k_attnfinal<<<256, 256, 0, stream>>>(Wa1, ba1, ga, bta, ySum, G, Wa1fbf, ba1f);
  k_main<<<1024, 256, 0, stream>>>(pq, ps, qT, kT, vT, idxb, Wp1f, bp1f, Wp2bf, bp2,
                                   Wa1fbf, ba1f, Wa2bf, ba2, aggT);
  k_epilogue<<<4096, 256, 0, stream>>>(aggT, We, be, fq, out);
}

// Round 4
// 316.578 us; speedup vs baseline: 4.3859x; 1.1127x over previous
//
#include <hip/hip_runtime.h>
#include <stdint.h>

#define NN 2048
#define MM 2048
#define NSAMP 131072   // B*N*K

typedef float  fv4 __attribute__((ext_vector_type(4)));
typedef short  bfv8 __attribute__((ext_vector_type(8)));
typedef short  bfv4 __attribute__((ext_vector_type(4)));
typedef unsigned short u16;
typedef unsigned long long u64;

__device__ inline u16 f2bf(float x){
  unsigned u = __float_as_uint(x);
  return (u16)((u + 0x7FFFu + ((u>>16)&1u)) >> 16);
}
__device__ inline float bf2f(u16 u){ return __uint_as_float(((unsigned)u)<<16); }
#define MFMA16 __builtin_amdgcn_mfma_f32_16x16x32_bf16

// ---------------------------------------------------------------------------
// prep: transpose qkv weights + bf16-pack Wp2 (row-major d,i) and Wa2 (d,h)
// ---------------------------------------------------------------------------
__global__ __launch_bounds__(256) void k_prep(
    const float* __restrict__ Wq, const float* __restrict__ Wk, const float* __restrict__ Wv,
    const float* __restrict__ Wp2, const float* __restrict__ Wa2,
    float* __restrict__ Wqt, float* __restrict__ Wkt, float* __restrict__ Wvt,
    u16* __restrict__ Wp2bf, u16* __restrict__ Wa2bf) {
  int gid = blockIdx.x * 256 + threadIdx.x;   // grid 64*256 = 16384
  if (gid < 8192)  { int c = gid >> 6, d = gid & 63;
    Wqt[gid] = Wq[d*128 + c]; Wkt[gid] = Wk[d*128 + c]; Wvt[gid] = Wv[d*128 + c]; }
  if (gid < 4096)  Wp2bf[gid] = f2bf(Wp2[gid]);     // (D,D) row-major
  if (gid < 16384) Wa2bf[gid] = f2bf(Wa2[gid]);     // (D,H) row-major
}

// ---------------------------------------------------------------------------
// q/k/v 1x1 conv -> n-major (point,d) layout
// ---------------------------------------------------------------------------
__global__ __launch_bounds__(256) void k_qkv(
    const float* __restrict__ fq, const float* __restrict__ fs,
    const float* __restrict__ Wqt, const float* __restrict__ Wkt, const float* __restrict__ Wvt,
    const float* __restrict__ bq, const float* __restrict__ bk, const float* __restrict__ bv,
    float* __restrict__ qT, float* __restrict__ kT, float* __restrict__ vT) {
  int bid = blockIdx.x;              // 3 * 4 * 256 = 3072
  int mat = bid >> 10;
  int rem = bid & 1023;
  int b  = rem >> 8;
  int n0 = (rem & 255) * 8;
  int t = threadIdx.x, d = t & 63, pc = t >> 6;
  const float* W   = mat == 0 ? Wqt : (mat == 1 ? Wkt : Wvt);
  const float* src = mat == 0 ? fq  : fs;
  const float* bia = mat == 0 ? bq  : (mat == 1 ? bk : bv);
  float* dst = mat == 0 ? qT : (mat == 1 ? kT : vT);
  int n_a = n0 + pc, n_b = n0 + 4 + pc;
  const float* sa = src + b * 128 * NN;
  float acc0 = bia[d], acc1 = acc0;
  #pragma unroll 8
  for (int c = 0; c < 128; ++c) {
    float w = W[c * 64 + d];
    acc0 = fmaf(w, sa[c * NN + n_a], acc0);
    acc1 = fmaf(w, sa[c * NN + n_b], acc1);
  }
  dst[(b * NN + n_a) * 64 + d] = acc0;
  dst[(b * NN + n_b) * 64 + d] = acc1;
}

// ---------------------------------------------------------------------------
// KNN: one wave per query. Per-lane: bitonic-sort two 16-candidate halves,
// bitonic keep-16 merge; then 16-round wave merge via shuffle-min.
// LDS list stride 17 u64 to avoid bank conflicts.
// ---------------------------------------------------------------------------
__global__ __launch_bounds__(256) void k_knn(
    const float* __restrict__ pq, const float* __restrict__ ps, int* __restrict__ idxb) {
  __shared__ u64 cand[4][64 * 17];
  int t = threadIdx.x, w = t >> 6, lane = t & 63;
  int qi = blockIdx.x * 4 + w;       // 0..8191
  int b = qi >> 11, n = qi & 2047;
  const float* pqb = pq + b * 3 * NN;
  const float* psb = ps + b * 3 * MM;
  float qx = pqb[n], qy = pqb[NN + n], qz = pqb[2 * NN + n];
  float qq = qx * qx + qy * qy + qz * qz;

  u64 A[16], Bv[16];
  #pragma unroll
  for (int j = 0; j < 16; ++j) {
    int m = lane + 64 * j;
    float sx = psb[m], sy = psb[MM + m], sz = psb[2 * MM + m];
    float ss  = sx * sx + sy * sy + sz * sz;
    float dot = qx * sx + qy * sy + qz * sz;
    float d2  = qq + ss - 2.f * dot;
    unsigned bu = __float_as_uint(d2);
    bu = (bu & 0x80000000u) ? ~bu : (bu | 0x80000000u);
    A[j] = (((u64)bu) << 32) | (unsigned)m;
  }
  #pragma unroll
  for (int j = 0; j < 16; ++j) {
    int m = lane + 64 * (j + 16);
    float sx = psb[m], sy = psb[MM + m], sz = psb[2 * MM + m];
    float ss  = sx * sx + sy * sy + sz * sz;
    float dot = qx * sx + qy * sy + qz * sz;
    float d2  = qq + ss - 2.f * dot;
    unsigned bu = __float_as_uint(d2);
    bu = (bu & 0x80000000u) ? ~bu : (bu | 0x80000000u);
    Bv[j] = (((u64)bu) << 32) | (unsigned)m;
  }
  // bitonic sort both halves ascending (fully unrolled networks)
  #pragma unroll
  for (int k = 2; k <= 16; k <<= 1) {
    #pragma unroll
    for (int j = k >> 1; j > 0; j >>= 1) {
      #pragma unroll
      for (int i = 0; i < 16; ++i) {
        int l = i ^ j;
        if (l > i) {
          bool up = ((i & k) == 0);
          { u64 x = A[i], y = A[l];
            bool sw = up ? (y < x) : (x < y);
            A[i] = sw ? y : x;  A[l] = sw ? x : y; }
          { u64 x = Bv[i], y = Bv[l];
            bool sw = up ? (y < x) : (x < y);
            Bv[i] = sw ? y : x; Bv[l] = sw ? x : y; }
        }
      }
    }
  }
  // keep-16: A[i] = min(A[i], Bv[15-i]) -> bitonic; clean to ascending
  #pragma unroll
  for (int i = 0; i < 16; ++i) {
    u64 y = Bv[15 - i];
    A[i] = A[i] < y ? A[i] : y;
  }
  #pragma unroll
  for (int j = 8; j > 0; j >>= 1) {
    #pragma unroll
    for (int i = 0; i < 16; ++i) {
      int l = i ^ j;
      if (l > i) {
        u64 x = A[i], y = A[l];
        bool sw = (y < x);
        A[i] = sw ? y : x;  A[l] = sw ? x : y;
      }
    }
  }
  #pragma unroll
  for (int i = 0; i < 16; ++i) cand[w][lane * 17 + i] = A[i];
  int head = 0;
  for (int r = 0; r < 16; ++r) {
    u64 v = (head < 16) ? cand[w][lane * 17 + head] : ~0ULL;
    u64 mv = v;
    #pragma unroll
    for (int off = 32; off > 0; off >>= 1) {
      u64 o = __shfl_xor(mv, off, 64);
      mv = o < mv ? o : mv;
    }
    if (v == mv) head++;
    if (lane == 0) idxb[qi * 16 + r] = (int)(mv & 0xFFFFFFFFu);
  }
}

// ---------------------------------------------------------------------------
// pos_rel first/second moments -> per-block partials (NO atomics)
// ---------------------------------------------------------------------------
__global__ __launch_bounds__(256) void k_posstats(
    const float* __restrict__ pq, const float* __restrict__ ps,
    const int* __restrict__ idxb, float* __restrict__ posPart) {
  __shared__ float red[4][9];
  int t = threadIdx.x;
  int gid = blockIdx.x * 256 + t;   // 131072
  int b = gid >> 15;
  int n = (gid >> 4) & 2047;
  int mi = idxb[gid];
  const float* pqb = pq + b * 3 * NN;
  const float* psb = ps + b * 3 * MM;
  float r0 = pqb[n]          - psb[mi];
  float r1 = pqb[NN + n]     - psb[MM + mi];
  float r2 = pqb[2 * NN + n] - psb[2 * MM + mi];
  float vals[9] = {r0, r1, r2, r0*r0, r0*r1, r0*r2, r1*r1, r1*r2, r2*r2};
  #pragma unroll
  for (int i = 0; i < 9; ++i) {
    float v = vals[i];
    #pragma unroll
    for (int off = 32; off > 0; off >>= 1) v += __shfl_xor(v, off, 64);
    if ((t & 63) == 0) red[t >> 6][i] = v;
  }
  __syncthreads();
  if (t < 9) posPart[blockIdx.x * 12 + t] =
      red[0][t] + red[1][t] + red[2][t] + red[3][t];
}

// ---------------------------------------------------------------------------
// reduce pos partials + fold pos-BN into Wp1/bp1 (exact)
// ---------------------------------------------------------------------------
__global__ __launch_bounds__(256) void k_posfinal(
    const float* __restrict__ Wp1, const float* __restrict__ bp1,
    const float* __restrict__ gp, const float* __restrict__ btp,
    const float* __restrict__ posPart, float* __restrict__ Wp1f, float* __restrict__ bp1f) {
  __shared__ float part[144];
  __shared__ float st[9];
  int t = threadIdx.x;
  if (t < 144) { int i = t >> 4, c = t & 15;
    float s = 0.f;
    for (int bb = c; bb < 512; bb += 16) s += posPart[bb * 12 + i];
    part[i * 16 + c] = s;
  }
  __syncthreads();
  if (t < 9) { float s = 0.f;
    #pragma unroll
    for (int c = 0; c < 16; ++c) s += part[t * 16 + c];
    st[t] = s;
  }
  __syncthreads();
  if (t < 64) {
    int d = t;
    const float invN = 1.f / (float)NSAMP;
    float m0 = st[0]*invN, m1 = st[1]*invN, m2 = st[2]*invN;
    float C00 = st[3]*invN - m0*m0, C01 = st[4]*invN - m0*m1, C02 = st[5]*invN - m0*m2;
    float C11 = st[6]*invN - m1*m1, C12 = st[7]*invN - m1*m2, C22 = st[8]*invN - m2*m2;
    float w0 = Wp1[d*3], w1 = Wp1[d*3+1], w2 = Wp1[d*3+2];
    float mean = w0*m0 + w1*m1 + w2*m2 + bp1[d];
    float var = w0*w0*C00 + w1*w1*C11 + w2*w2*C22 + 2.f*(w0*w1*C01 + w0*w2*C02 + w1*w2*C12);
    float scale = gp[d] * rsqrtf(var + 1e-5f);
    Wp1f[d*3]   = scale * w0;
    Wp1f[d*3+1] = scale * w1;
    Wp1f[d*3+2] = scale * w2;
    bp1f[d] = btp[d] + scale * (bp1[d] - mean);
  }
}

// ---------------------------------------------------------------------------
// y-stats: per-block Gram via MFMA (Y Y^T), partials to Gpart (= d_out scratch)
// ---------------------------------------------------------------------------
__global__ __launch_bounds__(256) void k_ystats(
    const float* __restrict__ pq, const float* __restrict__ ps,
    const float* __restrict__ qT, const float* __restrict__ kT,
    const int* __restrict__ idxb,
    const float* __restrict__ Wp1f, const float* __restrict__ bp1f,
    const u16* __restrict__ Wp2bf, const float* __restrict__ bp2,
    float* __restrict__ Gpart, float* __restrict__ ySumPart) {
  __shared__ __align__(16) unsigned char smem[21760];
  u16*   hp   = (u16*)smem;                 // [64 s][72 i] bf16
  u16*   y2   = (u16*)(smem + 9216);        // [64 d][72 s] bf16
  float* r3   = (float*)(smem + 18432);     // 192
  float* qc   = (float*)(smem + 19200);     // 256
  int*   idxA = (int*)(smem + 20224);       // 64
  float* sWp1 = (float*)(smem + 20480);     // 192
  float* sbp1 = (float*)(smem + 21248);     // 64
  float* sbp2 = (float*)(smem + 21504);     // 64

  const int t = threadIdx.x;
  const int w = t >> 6, l = t & 63, lq = l >> 4, ln = l & 15;
  const int d0 = 16*w + lq*4;

  if (t < 192) sWp1[t] = Wp1f[t];
  if (t < 64){ sbp1[t] = bp1f[t]; sbp2[t] = bp2[t]; }

  bfv8 Ape[2];
  #pragma unroll
  for (int kk = 0; kk < 2; ++kk)
    Ape[kk] = *(const bfv8*)(Wp2bf + (16*w + ln)*64 + kk*32 + lq*8);

  fv4 gacc[4];
  #pragma unroll
  for (int nt = 0; nt < 4; ++nt) gacc[nt] = (fv4){0.f,0.f,0.f,0.f};
  float ysacc = 0.f;
  __syncthreads();

  for (int ch = 0; ch < 8; ++ch) {
    const int p0 = blockIdx.x * 32 + ch * 4;
    const int b  = p0 >> 11;
    const int bN = b * 2048;
    if (t < 64) idxA[t] = idxb[p0*16 + t];
    qc[t] = qT[(p0 + (t>>6))*64 + (t & 63)];
    __syncthreads();
    if (t < 192) { int c = t >> 6, s = t & 63; int n = (p0 + (s>>4)) & 2047;
      r3[c*64 + s] = pq[(b*3+c)*NN + n] - ps[(b*3+c)*MM + idxA[s]]; }
    __syncthreads();
    { int s = t >> 2, iq = t & 3;
      float r0 = r3[s], r1 = r3[64+s], r2 = r3[128+s];
      u16 tmp[16];
      #pragma unroll
      for (int e = 0; e < 16; ++e) { int i = iq*16 + e;
        float v = sbp1[i] + sWp1[i*3]*r0 + sWp1[i*3+1]*r1 + sWp1[i*3+2]*r2;
        tmp[e] = f2bf(fmaxf(v, 0.f)); }
      *(bfv8*)&hp[s*72 + iq*16]     = *(const bfv8*)&tmp[0];
      *(bfv8*)&hp[s*72 + iq*16 + 8] = *(const bfv8*)&tmp[8];
    }
    __syncthreads();
    {
      fv4 pe[4];
      #pragma unroll
      for (int nt = 0; nt < 4; ++nt) {
        fv4 acc = {0.f,0.f,0.f,0.f};
        #pragma unroll
        for (int kk = 0; kk < 2; ++kk) {
          bfv8 bb = *(const bfv8*)&hp[(nt*16 + ln)*72 + kk*32 + lq*8];
          acc = MFMA16(Ape[kk], bb, acc, 0, 0, 0);
        }
        pe[nt] = acc;
      }
      fv4 bp2q = *(const fv4*)&sbp2[d0];
      #pragma unroll
      for (int nt = 0; nt < 4; ++nt) {
        int s = nt*16 + ln;
        int mi = idxA[s];
        fv4 kg = *(const fv4*)(kT + (bN + mi)*64 + d0);
        fv4 qv = *(const fv4*)&qc[nt*64 + d0];
        fv4 yv = qv - kg + pe[nt] + bp2q;
        #pragma unroll
        for (int r = 0; r < 4; ++r) y2[(d0 + r)*72 + s] = f2bf(yv[r]);
      }
    }
    __syncthreads();
    // Gram: G += Y Y^T  (wave w owns rows [16w,16w+16))
    #pragma unroll
    for (int kk = 0; kk < 2; ++kk) {
      bfv8 aa = *(const bfv8*)&y2[(16*w + ln)*72 + kk*32 + lq*8];
      #pragma unroll
      for (int nt = 0; nt < 4; ++nt) {
        bfv8 bb = *(const bfv8*)&y2[(nt*16 + ln)*72 + kk*32 + lq*8];
        gacc[nt] = MFMA16(aa, bb, gacc[nt], 0, 0, 0);
      }
    }
    if (t < 64) {
      float s = 0.f;
      #pragma unroll
      for (int ss = 0; ss < 64; ++ss) s += bf2f(y2[t*72 + ss]);
      ysacc += s;
    }
    __syncthreads();
  }
  #pragma unroll
  for (int nt = 0; nt < 4; ++nt)
    #pragma unroll
    for (int r = 0; r < 4; ++r)
      Gpart[blockIdx.x*4096 + (16*w + lq*4 + r)*64 + nt*16 + ln] = gacc[nt][r];
  if (t < 64) ySumPart[blockIdx.x*64 + t] = ysacc;
}

// ---------------------------------------------------------------------------
// reduce Gram / ySum partials (no atomics anywhere)
// ---------------------------------------------------------------------------
__global__ __launch_bounds__(256) void k_gred(
    const float* __restrict__ Gpart, const float* __restrict__ ySumPart,
    float* __restrict__ G, float* __restrict__ ySum) {
  int bid = blockIdx.x, t = threadIdx.x;   // grid 17
  if (bid < 16) {
    int j = bid*256 + t;
    float s = 0.f;
    for (int p = 0; p < 256; ++p) s += Gpart[p*4096 + j];
    G[j] = s;
  } else if (t < 64) {
    float s = 0.f;
    for (int p = 0; p < 256; ++p) s += ySumPart[p*64 + t];
    ySum[t] = s;
  }
}

// ---------------------------------------------------------------------------
// fold attn-BN into Wa1/ba1; emit bf16 Wa1f
// ---------------------------------------------------------------------------
__global__ __launch_bounds__(256) void k_attnfinal(
    const float* __restrict__ Wa1, const float* __restrict__ ba1,
    const float* __restrict__ ga, const float* __restrict__ bta,
    const float* __restrict__ ySum, const float* __restrict__ G,
    u16* __restrict__ Wa1fbf, float* __restrict__ ba1f) {
  __shared__ float red[256];
  __shared__ float mu[64];
  __shared__ float sc[1];
  int h = blockIdx.x, t = threadIdx.x;
  const float invN = 1.f / (float)NSAMP;
  if (t < 64) mu[t] = ySum[t] * invN;
  __syncthreads();
  float acc = 0.f;
  #pragma unroll
  for (int e = 0; e < 16; ++e) {
    int pi = t*16 + e, i = pi >> 6, j = pi & 63;
    float cov = G[pi]*invN - mu[i]*mu[j];
    acc += Wa1[h*64 + i] * Wa1[h*64 + j] * cov;
  }
  red[t] = acc;
  __syncthreads();
  for (int s = 128; s > 0; s >>= 1) { if (t < s) red[t] += red[t + s]; __syncthreads(); }
  float var = red[0];
  __syncthreads();
  red[t] = (t < 64) ? Wa1[h*64 + t] * mu[t] : 0.f;
  __syncthreads();
  for (int s = 128; s > 0; s >>= 1) { if (t < s) red[t] += red[t + s]; __syncthreads(); }
  if (t == 0) {
    float mean  = red[0] + ba1[h];
    float scale = ga[h] * rsqrtf(var + 1e-5f);
    sc[0] = scale;
    ba1f[h] = bta[h] + scale * (ba1[h] - mean);
  }
  __syncthreads();
  if (t < 64) Wa1fbf[h*64 + t] = f2bf(sc[0] * Wa1[h*64 + t]);
}

// ---------------------------------------------------------------------------
// main fused kernel (MFMA)
// ---------------------------------------------------------------------------
__global__ __launch_bounds__(256) void k_main(
    const float* __restrict__ pq, const float* __restrict__ ps,
    const float* __restrict__ qT, const float* __restrict__ kT, const float* __restrict__ vT,
    const int* __restrict__ idxb,
    const float* __restrict__ Wp1f, const float* __restrict__ bp1f,
    const u16* __restrict__ Wp2bf, const float* __restrict__ bp2,
    const u16* __restrict__ Wa1fbf, const float* __restrict__ ba1f,
    const u16* __restrict__ Wa2bf, const float* __restrict__ ba2,
    float* __restrict__ aggT) {
  __shared__ __align__(16) unsigned char smem[65024];
  u16*   hp   = (u16*)smem;                    // [64 s][72 i] bf16 (aliases ha)
  u16*   ha   = (u16*)smem;                    // [64 s][264 h] bf16
  u16*   ylds = (u16*)(smem + 33792);          // [64 s][72 d] bf16 (aliases at)
  float* at   = (float*)(smem + 33792);        // [64 s][68 d] f32
  u16*   vt   = (u16*)(smem + 51200);          // [64 s][72 d] bf16
  float* r3   = (float*)(smem + 60416);        // 192
  float* qc   = (float*)(smem + 61184);        // 256
  int*   idxA = (int*)(smem + 62208);          // 64
  float* sWp1 = (float*)(smem + 62464);        // 192
  float* sbp1 = (float*)(smem + 63232);        // 64
  float* sbp2 = (float*)(smem + 63488);        // 64
  float* sba1 = (float*)(smem + 63744);        // 256
  float* sba2 = (float*)(smem + 64768);        // 64

  const int t = threadIdx.x;
  const int w = t >> 6, l = t & 63, lq = l >> 4, ln = l & 15;
  const int d0 = 16*w + lq*4;

  if (t < 192) sWp1[t] = Wp1f[t];
  if (t < 64){ sbp1[t] = bp1f[t]; sbp2[t] = bp2[t]; sba2[t] = ba2[t]; }
  sba1[t] = ba1f[t];

  bfv8 Ape[2], A1[4][2], A2[8];
  #pragma unroll
  for (int kk = 0; kk < 2; ++kk)
    Ape[kk] = *(const bfv8*)(Wp2bf + (16*w + ln)*64 + kk*32 + lq*8);
  #pragma unroll
  for (int mt = 0; mt < 4; ++mt)
    #pragma unroll
    for (int kk = 0; kk < 2; ++kk)
      A1[mt][kk] = *(const bfv8*)(Wa1fbf + (64*w + mt*16 + ln)*64 + kk*32 + lq*8);
  #pragma unroll
  for (int kk = 0; kk < 8; ++kk)
    A2[kk] = *(const bfv8*)(Wa2bf + (16*w + ln)*256 + kk*32 + lq*8);
  __syncthreads();

  for (int ch = 0; ch < 2; ++ch) {
    const int p0 = blockIdx.x * 8 + ch * 4;
    const int b  = p0 >> 11;
    const int bN = b * 2048;
    if (t < 64) idxA[t] = idxb[p0*16 + t];
    qc[t] = qT[(p0 + (t>>6))*64 + (t & 63)];
    __syncthreads();
    if (t < 192) { int c = t >> 6, s = t & 63; int n = (p0 + (s>>4)) & 2047;
      r3[c*64 + s] = pq[(b*3+c)*NN + n] - ps[(b*3+c)*MM + idxA[s]]; }
    __syncthreads();
    { int s = t >> 2, iq = t & 3;
      float r0 = r3[s], r1 = r3[64+s], r2 = r3[128+s];
      u16 tmp[16];
      #pragma unroll
      for (int e = 0; e < 16; ++e) { int i = iq*16 + e;
        float v = sbp1[i] + sWp1[i*3]*r0 + sWp1[i*3+1]*r1 + sWp1[i*3+2]*r2;
        tmp[e] = f2bf(fmaxf(v, 0.f)); }
      *(bfv8*)&hp[s*72 + iq*16]     = *(const bfv8*)&tmp[0];
      *(bfv8*)&hp[s*72 + iq*16 + 8] = *(const bfv8*)&tmp[8];
    }
    __syncthreads();
    {
      fv4 pe[4];
      #pragma unroll
      for (int nt = 0; nt < 4; ++nt) {
        fv4 acc = {0.f,0.f,0.f,0.f};
        #pragma unroll
        for (int kk = 0; kk < 2; ++kk) {
          bfv8 bb = *(const bfv8*)&hp[(nt*16 + ln)*72 + kk*32 + lq*8];
          acc = MFMA16(Ape[kk], bb, acc, 0, 0, 0);
        }
        pe[nt] = acc;
      }
      fv4 bp2q = *(const fv4*)&sbp2[d0];
      #pragma unroll
      for (int nt = 0; nt < 4; ++nt) {
        int s = nt*16 + ln;
        int mi = idxA[s];
        fv4 kg = *(const fv4*)(kT + (bN + mi)*64 + d0);
        fv4 vg = *(const fv4*)(vT + (bN + mi)*64 + d0);
        fv4 qv = *(const fv4*)&qc[nt*64 + d0];
        fv4 pv = pe[nt] + bp2q;
        fv4 yv = qv - kg + pv;
        fv4 vv = vg + pv;
        u16 yp[4], vp[4];
        #pragma unroll
        for (int r = 0; r < 4; ++r) { yp[r] = f2bf(yv[r]); vp[r] = f2bf(vv[r]); }
        *(bfv4*)&ylds[s*72 + d0] = *(const bfv4*)yp;
        *(bfv4*)&vt[s*72 + d0]   = *(const bfv4*)vp;
      }
    }
    __syncthreads();
    // GEMM1: a1 = Wa1f @ y, +ba1f, relu -> ha bf16 [s][h]
    #pragma unroll
    for (int nt = 0; nt < 4; ++nt) {
      int s = nt*16 + ln;
      bfv8 b0 = *(const bfv8*)&ylds[s*72 + lq*8];
      bfv8 b1 = *(const bfv8*)&ylds[s*72 + 32 + lq*8];
      #pragma unroll
      for (int mt = 0; mt < 4; ++mt) {
        fv4 acc = {0.f,0.f,0.f,0.f};
        acc = MFMA16(A1[mt][0], b0, acc, 0, 0, 0);
        acc = MFMA16(A1[mt][1], b1, acc, 0, 0, 0);
        int h0 = 64*w + mt*16 + lq*4;
        fv4 bq = *(const fv4*)&sba1[h0];
        u16 hv[4];
        #pragma unroll
        for (int r = 0; r < 4; ++r) hv[r] = f2bf(fmaxf(acc[r] + bq[r], 0.f));
        *(bfv4*)&ha[s*264 + h0] = *(const bfv4*)hv;
      }
    }
    __syncthreads();
    // GEMM2: a2 = Wa2 @ ha, +ba2 -> at f32 [s][d]
    {
      fv4 acc2[4];
      #pragma unroll
      for (int nt = 0; nt < 4; ++nt) acc2[nt] = (fv4){0.f,0.f,0.f,0.f};
      #pragma unroll
      for (int kk = 0; kk < 8; ++kk) {
        #pragma unroll
        for (int nt = 0; nt < 4; ++nt) {
          bfv8 bb = *(const bfv8*)&ha[(nt*16 + ln)*264 + kk*32 + lq*8];
          acc2[nt] = MFMA16(A2[kk], bb, acc2[nt], 0, 0, 0);
        }
      }
      fv4 ba2q = *(const fv4*)&sba2[d0];
      #pragma unroll
      for (int nt = 0; nt < 4; ++nt) {
        int s = nt*16 + ln;
        fv4 o = acc2[nt] + ba2q;
        *(fv4*)&at[s*68 + d0] = o;
      }
    }
    __syncthreads();
    // softmax over K + weighted val sum
    {
      int dd = t & 63, pt = t >> 6;
      float a[16];
      #pragma unroll
      for (int k = 0; k < 16; ++k) a[k] = at[(pt*16 + k)*68 + dd];
      float mx = a[0];
      #pragma unroll
      for (int k = 1; k < 16; ++k) mx = fmaxf(mx, a[k]);
      float sum = 0.f, num = 0.f;
      #pragma unroll
      for (int k = 0; k < 16; ++k) {
        float e = __expf(a[k] - mx);
        sum += e;
        num += e * bf2f(vt[(pt*16 + k)*72 + dd]);
      }
      aggT[(p0 + pt)*64 + dd] = num / sum;
    }
    __syncthreads();
  }
}

// ---------------------------------------------------------------------------
// epilogue: out[b,c,n] = We[c,:]·agg[b,:,n] + be[c] + fq[b,c,n]
// ---------------------------------------------------------------------------
__global__ __launch_bounds__(256) void k_epilogue(
    const float* __restrict__ aggT, const float* __restrict__ We,
    const float* __restrict__ be, const float* __restrict__ fq, float* __restrict__ out) {
  int bid = blockIdx.x;               // 4 * 32 * 32 = 4096
  int b  = bid >> 10;
  int c0 = ((bid >> 5) & 31) * 4;
  int n0 = (bid & 31) * 64;
  int t = threadIdx.x;
  int n = n0 + (t & 63), c = c0 + (t >> 6);
  float acc = be[c];
  const float* ag = aggT + (b * NN + n) * 64;
  const float* wr = We + c * 64;
  #pragma unroll 8
  for (int dd = 0; dd < 64; ++dd) acc = fmaf(wr[dd], ag[dd], acc);
  int o = (b * 128 + c) * NN + n;
  out[o] = acc + fq[o];
}

// ---------------------------------------------------------------------------
extern "C" void kernel_launch(void* const* d_in, const int* in_sizes, int n_in,
                              void* d_out, int out_size, void* d_ws, size_t ws_size,
                              hipStream_t stream) {
  (void)in_sizes; (void)n_in; (void)out_size; (void)ws_size;
  const float* pq  = (const float*)d_in[0];
  const float* fq  = (const float*)d_in[1];
  const float* ps  = (const float*)d_in[2];
  const float* fs  = (const float*)d_in[3];
  const float* Wq  = (const float*)d_in[4];  const float* bq  = (const float*)d_in[5];
  const float* Wk  = (const float*)d_in[6];  const float* bk  = (const float*)d_in[7];
  const float* Wv  = (const float*)d_in[8];  const float* bv  = (const float*)d_in[9];
  const float* Wp1 = (const float*)d_in[10]; const float* bp1 = (const float*)d_in[11];
  const float* gp  = (const float*)d_in[12]; const float* btp = (const float*)d_in[13];
  const float* Wp2 = (const float*)d_in[14]; const float* bp2 = (const float*)d_in[15];
  const float* Wa1 = (const float*)d_in[16]; const float* ba1 = (const float*)d_in[17];
  const float* ga  = (const float*)d_in[18]; const float* bta = (const float*)d_in[19];
  const float* Wa2 = (const float*)d_in[20]; const float* ba2 = (const float*)d_in[21];
  const float* We  = (const float*)d_in[22]; const float* be  = (const float*)d_in[23];
  float* ws = (float*)d_ws;
  float* qT    = ws;
  float* kT    = ws + 524288;
  float* vT    = ws + 1048576;
  float* aggT  = ws + 1572864;
  int*   idxb  = (int*)(ws + 2097152);
  float* Wqt   = ws + 2228224;
  float* Wkt   = ws + 2236416;
  float* Wvt   = ws + 2244608;
  float* Wp1f  = ws + 2252800;
  float* bp1f  = ws + 2252992;
  float* ba1f  = ws + 2253056;
  float* G     = ws + 2253376;
  float* ySum  = ws + 2257472;
  float* ySumP = ws + 2257536;
  u16*   Wp2bf  = (u16*)(ws + 2273920);
  u16*   Wa2bf  = (u16*)(ws + 2275968);
  u16*   Wa1fbf = (u16*)(ws + 2284160);
  // d_out doubles as scratch: posPart (512*12 floats) then Gpart (256*4096
  // floats). Both fully consumed before k_epilogue overwrites d_out.
  float* posPart = (float*)d_out;
  float* Gpart   = (float*)d_out;
  float* out     = (float*)d_out;

  k_prep<<<64, 256, 0, stream>>>(Wq, Wk, Wv, Wp2, Wa2, Wqt, Wkt, Wvt, Wp2bf, Wa2bf);
  k_qkv<<<3072, 256, 0, stream>>>(fq, fs, Wqt, Wkt, Wvt, bq, bk, bv, qT, kT, vT);
  k_knn<<<2048, 256, 0, stream>>>(pq, ps, idxb);
  k_posstats<<<512, 256, 0, stream>>>(pq, ps, idxb, posPart);
  k_posfinal<<<1, 256, 0, stream>>>(Wp1, bp1, gp, btp, posPart, Wp1f, bp1f);
  k_ystats<<<256, 256, 0, stream>>>(pq, ps, qT, kT, idxb, Wp1f, bp1f, Wp2bf, bp2,
                                    Gpart, ySumP);
  k_gred<<<17, 256, 0, stream>>>(Gpart, ySumP, G, ySum);
  k_attnfinal<<<256, 256, 0, stream>>>(Wa1, ba1, ga, bta, ySum, G, Wa1fbf, ba1f);
  k_main<<<1024, 256, 0, stream>>>(pq, ps, qT, kT, vT, idxb, Wp1f, bp1f, Wp2bf, bp2,
                                   Wa1fbf, ba1f, Wa2bf, ba2, aggT);
  k_epilogue<<<4096, 256, 0, stream>>>(aggT, We, be, fq, out);
}

// Round 5
// 254.439 us; speedup vs baseline: 5.4570x; 1.2442x over previous
//
#include <hip/hip_runtime.h>
#include <stdint.h>

#define NN 2048
#define MM 2048
#define NSAMP 131072   // B*N*K

typedef float  fv4 __attribute__((ext_vector_type(4)));
typedef short  bfv8 __attribute__((ext_vector_type(8)));
typedef short  bfv4 __attribute__((ext_vector_type(4)));
typedef unsigned short u16;
typedef unsigned long long u64;

__device__ inline u16 f2bf(float x){
  unsigned u = __float_as_uint(x);
  return (u16)((u + 0x7FFFu + ((u>>16)&1u)) >> 16);
}
__device__ inline float bf2f(u16 u){ return __uint_as_float(((unsigned)u)<<16); }
#define MFMA16 __builtin_amdgcn_mfma_f32_16x16x32_bf16

// ---------------------------------------------------------------------------
// prep: bf16-pack all weights (already k-contiguous row-major) + psP float4
// ---------------------------------------------------------------------------
__global__ __launch_bounds__(256) void k_prep(
    const float* __restrict__ Wq, const float* __restrict__ Wk, const float* __restrict__ Wv,
    const float* __restrict__ Wp2, const float* __restrict__ Wa2, const float* __restrict__ We,
    const float* __restrict__ ps,
    u16* __restrict__ Wqbf, u16* __restrict__ Wkbf, u16* __restrict__ Wvbf,
    u16* __restrict__ Wp2bf, u16* __restrict__ Wa2bf, u16* __restrict__ Webf,
    fv4* __restrict__ psP) {
  int gid = blockIdx.x * 256 + threadIdx.x;   // grid 64*256 = 16384
  if (gid < 8192)  { Wqbf[gid] = f2bf(Wq[gid]); Wkbf[gid] = f2bf(Wk[gid]);
                     Wvbf[gid] = f2bf(Wv[gid]); Webf[gid] = f2bf(We[gid]); }
  if (gid < 4096)  Wp2bf[gid] = f2bf(Wp2[gid]);     // (D,D) row-major
  if (gid < 16384) Wa2bf[gid] = f2bf(Wa2[gid]);     // (D,H) row-major
  if (gid < 8192)  { int b = gid >> 11, m = gid & 2047;
    float x = ps[(b*3+0)*MM + m], y = ps[(b*3+1)*MM + m], z = ps[(b*3+2)*MM + m];
    fv4 p; p.x = x; p.y = y; p.z = z; p.w = x*x + y*y + z*z;
    psP[gid] = p; }
}

// ---------------------------------------------------------------------------
// pack: transpose fq/fs (B,C,N) fp32 -> (B,N,C) bf16 via LDS tile
// ---------------------------------------------------------------------------
__global__ __launch_bounds__(256) void k_pack(
    const float* __restrict__ fq, const float* __restrict__ fs,
    u16* __restrict__ xq, u16* __restrict__ xs) {
  __shared__ float tile[128][66];
  int bid = blockIdx.x;         // 256: [0,128) fq, [128,256) fs
  const float* src = bid < 128 ? fq : fs;
  u16* dst = bid < 128 ? xq : xs;
  int r = bid & 127;
  int b = r >> 5, n0 = (r & 31) * 64;
  int t = threadIdx.x;
  int nj = t & 63, cq = t >> 6;
  #pragma unroll 4
  for (int it = 0; it < 32; ++it) {
    int c = it * 4 + cq;
    tile[c][nj] = src[(b*128 + c)*NN + n0 + nj];
  }
  __syncthreads();
  int n = t >> 2, q = t & 3;
  #pragma unroll
  for (int j = 0; j < 4; ++j) {
    int oct = q * 4 + j;
    u16 tmp[8];
    #pragma unroll
    for (int e = 0; e < 8; ++e) tmp[e] = f2bf(tile[oct*8 + e][n]);
    *(bfv8*)&dst[(b*NN + n0 + n)*128 + oct*8] = *(const bfv8*)tmp;
  }
}

// ---------------------------------------------------------------------------
// q/k/v via MFMA: per block 32 points, wave w = mtile w, 3 mats each
// ---------------------------------------------------------------------------
__global__ __launch_bounds__(256) void k_qkv(
    const u16* __restrict__ xq, const u16* __restrict__ xs,
    const u16* __restrict__ Wqbf, const u16* __restrict__ Wkbf, const u16* __restrict__ Wvbf,
    const float* __restrict__ bq, const float* __restrict__ bk, const float* __restrict__ bv,
    float* __restrict__ qT, float* __restrict__ kT, float* __restrict__ vT) {
  __shared__ u16 tile[2][32 * 136];
  int bid = blockIdx.x;            // 256
  int b = bid >> 6, p0 = (bid & 63) * 32;
  int t = threadIdx.x;
  int w = t >> 6, l = t & 63, lq = l >> 4, ln = l & 15;
  {
    int n = t >> 3, i8 = t & 7;
    const u16* s0 = xq + (b*NN + p0 + n)*128 + i8*16;
    const u16* s1 = xs + (b*NN + p0 + n)*128 + i8*16;
    *(bfv8*)&tile[0][n*136 + i8*16]     = *(const bfv8*)s0;
    *(bfv8*)&tile[0][n*136 + i8*16 + 8] = *(const bfv8*)(s0 + 8);
    *(bfv8*)&tile[1][n*136 + i8*16]     = *(const bfv8*)s1;
    *(bfv8*)&tile[1][n*136 + i8*16 + 8] = *(const bfv8*)(s1 + 8);
  }
  bfv8 A[3][4];
  #pragma unroll
  for (int mat = 0; mat < 3; ++mat) {
    const u16* W = mat == 0 ? Wqbf : (mat == 1 ? Wkbf : Wvbf);
    #pragma unroll
    for (int kk = 0; kk < 4; ++kk)
      A[mat][kk] = *(const bfv8*)(W + (w*16 + ln)*128 + kk*32 + lq*8);
  }
  __syncthreads();
  fv4 acc[3][2];
  #pragma unroll
  for (int mat = 0; mat < 3; ++mat) {
    const u16* tl = tile[mat == 0 ? 0 : 1];
    #pragma unroll
    for (int nt = 0; nt < 2; ++nt) {
      fv4 a = {0.f,0.f,0.f,0.f};
      #pragma unroll
      for (int kk = 0; kk < 4; ++kk) {
        bfv8 bb = *(const bfv8*)&tl[(nt*16 + ln)*136 + kk*32 + lq*8];
        a = MFMA16(A[mat][kk], bb, a, 0, 0, 0);
      }
      acc[mat][nt] = a;
    }
  }
  #pragma unroll
  for (int mat = 0; mat < 3; ++mat) {
    float* dst = mat == 0 ? qT : (mat == 1 ? kT : vT);
    const float* bia = mat == 0 ? bq : (mat == 1 ? bk : bv);
    fv4 bq4 = *(const fv4*)&bia[w*16 + lq*4];
    #pragma unroll
    for (int nt = 0; nt < 2; ++nt) {
      fv4 o = acc[mat][nt] + bq4;
      *(fv4*)&dst[(b*NN + p0 + nt*16 + ln)*64 + w*16 + lq*4] = o;
    }
  }
}

// ---------------------------------------------------------------------------
// KNN: one wave per query; psP float4 candidates; bitonic sort + keep-16;
// wave merge via shuffle-min. Block 128 (2 waves) for occupancy.
// ---------------------------------------------------------------------------
__global__ __launch_bounds__(128) void k_knn(
    const float* __restrict__ pq, const fv4* __restrict__ psP, int* __restrict__ idxb) {
  __shared__ u64 cand[2][64 * 17];
  int t = threadIdx.x, w = t >> 6, lane = t & 63;
  int qi = blockIdx.x * 2 + w;       // 0..8191
  int b = qi >> 11, n = qi & 2047;
  const float* pqb = pq + b * 3 * NN;
  const fv4* psb = psP + b * 2048;
  float qx = pqb[n], qy = pqb[NN + n], qz = pqb[2 * NN + n];
  float qq = qx * qx + qy * qy + qz * qz;

  u64 A[16], Bv[16];
  #pragma unroll
  for (int j = 0; j < 16; ++j) {
    int m = lane + 64 * j;
    fv4 P = psb[m];
    float dot = qx * P.x + qy * P.y + qz * P.z;
    float d2  = qq + P.w - 2.f * dot;
    unsigned bu = __float_as_uint(d2);
    bu = (bu & 0x80000000u) ? ~bu : (bu | 0x80000000u);
    A[j] = (((u64)bu) << 32) | (unsigned)m;
  }
  #pragma unroll
  for (int j = 0; j < 16; ++j) {
    int m = lane + 64 * (j + 16);
    fv4 P = psb[m];
    float dot = qx * P.x + qy * P.y + qz * P.z;
    float d2  = qq + P.w - 2.f * dot;
    unsigned bu = __float_as_uint(d2);
    bu = (bu & 0x80000000u) ? ~bu : (bu | 0x80000000u);
    Bv[j] = (((u64)bu) << 32) | (unsigned)m;
  }
  #pragma unroll
  for (int k = 2; k <= 16; k <<= 1) {
    #pragma unroll
    for (int j = k >> 1; j > 0; j >>= 1) {
      #pragma unroll
      for (int i = 0; i < 16; ++i) {
        int l2 = i ^ j;
        if (l2 > i) {
          bool up = ((i & k) == 0);
          { u64 x = A[i], y = A[l2];
            bool sw = up ? (y < x) : (x < y);
            A[i] = sw ? y : x;  A[l2] = sw ? x : y; }
          { u64 x = Bv[i], y = Bv[l2];
            bool sw = up ? (y < x) : (x < y);
            Bv[i] = sw ? y : x; Bv[l2] = sw ? x : y; }
        }
      }
    }
  }
  #pragma unroll
  for (int i = 0; i < 16; ++i) {
    u64 y = Bv[15 - i];
    A[i] = A[i] < y ? A[i] : y;
  }
  #pragma unroll
  for (int j = 8; j > 0; j >>= 1) {
    #pragma unroll
    for (int i = 0; i < 16; ++i) {
      int l2 = i ^ j;
      if (l2 > i) {
        u64 x = A[i], y = A[l2];
        bool sw = (y < x);
        A[i] = sw ? y : x;  A[l2] = sw ? x : y;
      }
    }
  }
  #pragma unroll
  for (int i = 0; i < 16; ++i) cand[w][lane * 17 + i] = A[i];
  int head = 0;
  for (int r = 0; r < 16; ++r) {
    u64 v = (head < 16) ? cand[w][lane * 17 + head] : ~0ULL;
    u64 mv = v;
    #pragma unroll
    for (int off = 32; off > 0; off >>= 1) {
      u64 o = __shfl_xor(mv, off, 64);
      mv = o < mv ? o : mv;
    }
    if (v == mv) head++;
    if (lane == 0) idxb[qi * 16 + r] = (int)(mv & 0xFFFFFFFFu);
  }
}

// ---------------------------------------------------------------------------
// pos_rel first/second moments -> per-block partials (NO atomics)
// ---------------------------------------------------------------------------
__global__ __launch_bounds__(256) void k_posstats(
    const float* __restrict__ pq, const float* __restrict__ ps,
    const int* __restrict__ idxb, float* __restrict__ posPart) {
  __shared__ float red[4][9];
  int t = threadIdx.x;
  int gid = blockIdx.x * 256 + t;   // 131072
  int b = gid >> 15;
  int n = (gid >> 4) & 2047;
  int mi = idxb[gid];
  const float* pqb = pq + b * 3 * NN;
  const float* psb = ps + b * 3 * MM;
  float r0 = pqb[n]          - psb[mi];
  float r1 = pqb[NN + n]     - psb[MM + mi];
  float r2 = pqb[2 * NN + n] - psb[2 * MM + mi];
  float vals[9] = {r0, r1, r2, r0*r0, r0*r1, r0*r2, r1*r1, r1*r2, r2*r2};
  #pragma unroll
  for (int i = 0; i < 9; ++i) {
    float v = vals[i];
    #pragma unroll
    for (int off = 32; off > 0; off >>= 1) v += __shfl_xor(v, off, 64);
    if ((t & 63) == 0) red[t >> 6][i] = v;
  }
  __syncthreads();
  if (t < 9) posPart[blockIdx.x * 12 + t] =
      red[0][t] + red[1][t] + red[2][t] + red[3][t];
}

// ---------------------------------------------------------------------------
// reduce pos partials + fold pos-BN into Wp1/bp1 (exact)
// ---------------------------------------------------------------------------
__global__ __launch_bounds__(256) void k_posfinal(
    const float* __restrict__ Wp1, const float* __restrict__ bp1,
    const float* __restrict__ gp, const float* __restrict__ btp,
    const float* __restrict__ posPart, float* __restrict__ Wp1f, float* __restrict__ bp1f) {
  __shared__ float part[144];
  __shared__ float st[9];
  int t = threadIdx.x;
  if (t < 144) { int i = t >> 4, c = t & 15;
    float s = 0.f;
    for (int bb = c; bb < 512; bb += 16) s += posPart[bb * 12 + i];
    part[i * 16 + c] = s;
  }
  __syncthreads();
  if (t < 9) { float s = 0.f;
    #pragma unroll
    for (int c = 0; c < 16; ++c) s += part[t * 16 + c];
    st[t] = s;
  }
  __syncthreads();
  if (t < 64) {
    int d = t;
    const float invN = 1.f / (float)NSAMP;
    float m0 = st[0]*invN, m1 = st[1]*invN, m2 = st[2]*invN;
    float C00 = st[3]*invN - m0*m0, C01 = st[4]*invN - m0*m1, C02 = st[5]*invN - m0*m2;
    float C11 = st[6]*invN - m1*m1, C12 = st[7]*invN - m1*m2, C22 = st[8]*invN - m2*m2;
    float w0 = Wp1[d*3], w1 = Wp1[d*3+1], w2 = Wp1[d*3+2];
    float mean = w0*m0 + w1*m1 + w2*m2 + bp1[d];
    float var = w0*w0*C00 + w1*w1*C11 + w2*w2*C22 + 2.f*(w0*w1*C01 + w0*w2*C02 + w1*w2*C12);
    float scale = gp[d] * rsqrtf(var + 1e-5f);
    Wp1f[d*3]   = scale * w0;
    Wp1f[d*3+1] = scale * w1;
    Wp1f[d*3+2] = scale * w2;
    bp1f[d] = btp[d] + scale * (bp1[d] - mean);
  }
}

// ---------------------------------------------------------------------------
// y-stats: per-block Gram via MFMA (Y Y^T), partials to Gpart (= d_out scratch)
// ---------------------------------------------------------------------------
__global__ __launch_bounds__(256) void k_ystats(
    const float* __restrict__ pq, const float* __restrict__ ps,
    const float* __restrict__ qT, const float* __restrict__ kT,
    const int* __restrict__ idxb,
    const float* __restrict__ Wp1f, const float* __restrict__ bp1f,
    const u16* __restrict__ Wp2bf, const float* __restrict__ bp2,
    float* __restrict__ Gpart, float* __restrict__ ySumPart) {
  __shared__ __align__(16) unsigned char smem[21760];
  u16*   hp   = (u16*)smem;                 // [64 s][72 i] bf16
  u16*   y2   = (u16*)(smem + 9216);        // [64 d][72 s] bf16
  float* r3   = (float*)(smem + 18432);     // 192
  float* qc   = (float*)(smem + 19200);     // 256
  int*   idxA = (int*)(smem + 20224);       // 64
  float* sWp1 = (float*)(smem + 20480);     // 192
  float* sbp1 = (float*)(smem + 21248);     // 64
  float* sbp2 = (float*)(smem + 21504);     // 64

  const int t = threadIdx.x;
  const int w = t >> 6, l = t & 63, lq = l >> 4, ln = l & 15;
  const int d0 = 16*w + lq*4;

  if (t < 192) sWp1[t] = Wp1f[t];
  if (t < 64){ sbp1[t] = bp1f[t]; sbp2[t] = bp2[t]; }

  bfv8 Ape[2];
  #pragma unroll
  for (int kk = 0; kk < 2; ++kk)
    Ape[kk] = *(const bfv8*)(Wp2bf + (16*w + ln)*64 + kk*32 + lq*8);

  fv4 gacc[4];
  #pragma unroll
  for (int nt = 0; nt < 4; ++nt) gacc[nt] = (fv4){0.f,0.f,0.f,0.f};
  float ysacc = 0.f;
  __syncthreads();

  for (int ch = 0; ch < 8; ++ch) {
    const int p0 = blockIdx.x * 32 + ch * 4;
    const int b  = p0 >> 11;
    const int bN = b * 2048;
    if (t < 64) idxA[t] = idxb[p0*16 + t];
    qc[t] = qT[(p0 + (t>>6))*64 + (t & 63)];
    __syncthreads();
    if (t < 192) { int c = t >> 6, s = t & 63; int n = (p0 + (s>>4)) & 2047;
      r3[c*64 + s] = pq[(b*3+c)*NN + n] - ps[(b*3+c)*MM + idxA[s]]; }
    __syncthreads();
    { int s = t >> 2, iq = t & 3;
      float r0 = r3[s], r1 = r3[64+s], r2 = r3[128+s];
      u16 tmp[16];
      #pragma unroll
      for (int e = 0; e < 16; ++e) { int i = iq*16 + e;
        float v = sbp1[i] + sWp1[i*3]*r0 + sWp1[i*3+1]*r1 + sWp1[i*3+2]*r2;
        tmp[e] = f2bf(fmaxf(v, 0.f)); }
      *(bfv8*)&hp[s*72 + iq*16]     = *(const bfv8*)&tmp[0];
      *(bfv8*)&hp[s*72 + iq*16 + 8] = *(const bfv8*)&tmp[8];
    }
    __syncthreads();
    {
      fv4 pe[4];
      #pragma unroll
      for (int nt = 0; nt < 4; ++nt) {
        fv4 acc = {0.f,0.f,0.f,0.f};
        #pragma unroll
        for (int kk = 0; kk < 2; ++kk) {
          bfv8 bb = *(const bfv8*)&hp[(nt*16 + ln)*72 + kk*32 + lq*8];
          acc = MFMA16(Ape[kk], bb, acc, 0, 0, 0);
        }
        pe[nt] = acc;
      }
      fv4 bp2q = *(const fv4*)&sbp2[d0];
      #pragma unroll
      for (int nt = 0; nt < 4; ++nt) {
        int s = nt*16 + ln;
        int mi = idxA[s];
        fv4 kg = *(const fv4*)(kT + (bN + mi)*64 + d0);
        fv4 qv = *(const fv4*)&qc[nt*64 + d0];
        fv4 yv = qv - kg + pe[nt] + bp2q;
        #pragma unroll
        for (int r = 0; r < 4; ++r) y2[(d0 + r)*72 + s] = f2bf(yv[r]);
      }
    }
    __syncthreads();
    #pragma unroll
    for (int kk = 0; kk < 2; ++kk) {
      bfv8 aa = *(const bfv8*)&y2[(16*w + ln)*72 + kk*32 + lq*8];
      #pragma unroll
      for (int nt = 0; nt < 4; ++nt) {
        bfv8 bb = *(const bfv8*)&y2[(nt*16 + ln)*72 + kk*32 + lq*8];
        gacc[nt] = MFMA16(aa, bb, gacc[nt], 0, 0, 0);
      }
    }
    if (t < 64) {
      float s = 0.f;
      #pragma unroll
      for (int ss = 0; ss < 64; ++ss) s += bf2f(y2[t*72 + ss]);
      ysacc += s;
    }
    __syncthreads();
  }
  #pragma unroll
  for (int nt = 0; nt < 4; ++nt)
    #pragma unroll
    for (int r = 0; r < 4; ++r)
      Gpart[blockIdx.x*4096 + (16*w + lq*4 + r)*64 + nt*16 + ln] = gacc[nt][r];
  if (t < 64) ySumPart[blockIdx.x*64 + t] = ysacc;
}

// ---------------------------------------------------------------------------
// reduce Gram / ySum partials
// ---------------------------------------------------------------------------
__global__ __launch_bounds__(256) void k_gred(
    const float* __restrict__ Gpart, const float* __restrict__ ySumPart,
    float* __restrict__ G, float* __restrict__ ySum) {
  int bid = blockIdx.x, t = threadIdx.x;   // grid 17
  if (bid < 16) {
    int j = bid*256 + t;
    float s = 0.f;
    for (int p = 0; p < 256; ++p) s += Gpart[p*4096 + j];
    G[j] = s;
  } else if (t < 64) {
    float s = 0.f;
    for (int p = 0; p < 256; ++p) s += ySumPart[p*64 + t];
    ySum[t] = s;
  }
}

// ---------------------------------------------------------------------------
// fold attn-BN into Wa1/ba1; emit bf16 Wa1f
// ---------------------------------------------------------------------------
__global__ __launch_bounds__(256) void k_attnfinal(
    const float* __restrict__ Wa1, const float* __restrict__ ba1,
    const float* __restrict__ ga, const float* __restrict__ bta,
    const float* __restrict__ ySum, const float* __restrict__ G,
    u16* __restrict__ Wa1fbf, float* __restrict__ ba1f) {
  __shared__ float red[256];
  __shared__ float mu[64];
  __shared__ float sc[1];
  int h = blockIdx.x, t = threadIdx.x;
  const float invN = 1.f / (float)NSAMP;
  if (t < 64) mu[t] = ySum[t] * invN;
  __syncthreads();
  float acc = 0.f;
  #pragma unroll
  for (int e = 0; e < 16; ++e) {
    int pi = t*16 + e, i = pi >> 6, j = pi & 63;
    float cov = G[pi]*invN - mu[i]*mu[j];
    acc += Wa1[h*64 + i] * Wa1[h*64 + j] * cov;
  }
  red[t] = acc;
  __syncthreads();
  for (int s = 128; s > 0; s >>= 1) { if (t < s) red[t] += red[t + s]; __syncthreads(); }
  float var = red[0];
  __syncthreads();
  red[t] = (t < 64) ? Wa1[h*64 + t] * mu[t] : 0.f;
  __syncthreads();
  for (int s = 128; s > 0; s >>= 1) { if (t < s) red[t] += red[t + s]; __syncthreads(); }
  if (t == 0) {
    float mean  = red[0] + ba1[h];
    float scale = ga[h] * rsqrtf(var + 1e-5f);
    sc[0] = scale;
    ba1f[h] = bta[h] + scale * (ba1[h] - mean);
  }
  __syncthreads();
  if (t < 64) Wa1fbf[h*64 + t] = f2bf(sc[0] * Wa1[h*64 + t]);
}

// ---------------------------------------------------------------------------
// main fused kernel (MFMA); emits agg as bf16 (d-contiguous)
// ---------------------------------------------------------------------------
__global__ __launch_bounds__(256) void k_main(
    const float* __restrict__ pq, const float* __restrict__ ps,
    const float* __restrict__ qT, const float* __restrict__ kT, const float* __restrict__ vT,
    const int* __restrict__ idxb,
    const float* __restrict__ Wp1f, const float* __restrict__ bp1f,
    const u16* __restrict__ Wp2bf, const float* __restrict__ bp2,
    const u16* __restrict__ Wa1fbf, const float* __restrict__ ba1f,
    const u16* __restrict__ Wa2bf, const float* __restrict__ ba2,
    u16* __restrict__ aggbf) {
  __shared__ __align__(16) unsigned char smem[65024];
  u16*   hp   = (u16*)smem;                    // [64 s][72 i] bf16 (aliases ha)
  u16*   ha   = (u16*)smem;                    // [64 s][264 h] bf16
  u16*   ylds = (u16*)(smem + 33792);          // [64 s][72 d] bf16 (aliases at)
  float* at   = (float*)(smem + 33792);        // [64 s][68 d] f32
  u16*   vt   = (u16*)(smem + 51200);          // [64 s][72 d] bf16
  float* r3   = (float*)(smem + 60416);        // 192
  float* qc   = (float*)(smem + 61184);        // 256
  int*   idxA = (int*)(smem + 62208);          // 64
  float* sWp1 = (float*)(smem + 62464);        // 192
  float* sbp1 = (float*)(smem + 63232);        // 64
  float* sbp2 = (float*)(smem + 63488);        // 64
  float* sba1 = (float*)(smem + 63744);        // 256
  float* sba2 = (float*)(smem + 64768);        // 64

  const int t = threadIdx.x;
  const int w = t >> 6, l = t & 63, lq = l >> 4, ln = l & 15;
  const int d0 = 16*w + lq*4;

  if (t < 192) sWp1[t] = Wp1f[t];
  if (t < 64){ sbp1[t] = bp1f[t]; sbp2[t] = bp2[t]; sba2[t] = ba2[t]; }
  sba1[t] = ba1f[t];

  bfv8 Ape[2], A1[4][2], A2[8];
  #pragma unroll
  for (int kk = 0; kk < 2; ++kk)
    Ape[kk] = *(const bfv8*)(Wp2bf + (16*w + ln)*64 + kk*32 + lq*8);
  #pragma unroll
  for (int mt = 0; mt < 4; ++mt)
    #pragma unroll
    for (int kk = 0; kk < 2; ++kk)
      A1[mt][kk] = *(const bfv8*)(Wa1fbf + (64*w + mt*16 + ln)*64 + kk*32 + lq*8);
  #pragma unroll
  for (int kk = 0; kk < 8; ++kk)
    A2[kk] = *(const bfv8*)(Wa2bf + (16*w + ln)*256 + kk*32 + lq*8);
  __syncthreads();

  for (int ch = 0; ch < 2; ++ch) {
    const int p0 = blockIdx.x * 8 + ch * 4;
    const int b  = p0 >> 11;
    const int bN = b * 2048;
    if (t < 64) idxA[t] = idxb[p0*16 + t];
    qc[t] = qT[(p0 + (t>>6))*64 + (t & 63)];
    __syncthreads();
    if (t < 192) { int c = t >> 6, s = t & 63; int n = (p0 + (s>>4)) & 2047;
      r3[c*64 + s] = pq[(b*3+c)*NN + n] - ps[(b*3+c)*MM + idxA[s]]; }
    __syncthreads();
    { int s = t >> 2, iq = t & 3;
      float r0 = r3[s], r1 = r3[64+s], r2 = r3[128+s];
      u16 tmp[16];
      #pragma unroll
      for (int e = 0; e < 16; ++e) { int i = iq*16 + e;
        float v = sbp1[i] + sWp1[i*3]*r0 + sWp1[i*3+1]*r1 + sWp1[i*3+2]*r2;
        tmp[e] = f2bf(fmaxf(v, 0.f)); }
      *(bfv8*)&hp[s*72 + iq*16]     = *(const bfv8*)&tmp[0];
      *(bfv8*)&hp[s*72 + iq*16 + 8] = *(const bfv8*)&tmp[8];
    }
    __syncthreads();
    {
      fv4 pe[4];
      #pragma unroll
      for (int nt = 0; nt < 4; ++nt) {
        fv4 acc = {0.f,0.f,0.f,0.f};
        #pragma unroll
        for (int kk = 0; kk < 2; ++kk) {
          bfv8 bb = *(const bfv8*)&hp[(nt*16 + ln)*72 + kk*32 + lq*8];
          acc = MFMA16(Ape[kk], bb, acc, 0, 0, 0);
        }
        pe[nt] = acc;
      }
      fv4 bp2q = *(const fv4*)&sbp2[d0];
      #pragma unroll
      for (int nt = 0; nt < 4; ++nt) {
        int s = nt*16 + ln;
        int mi = idxA[s];
        fv4 kg = *(const fv4*)(kT + (bN + mi)*64 + d0);
        fv4 vg = *(const fv4*)(vT + (bN + mi)*64 + d0);
        fv4 qv = *(const fv4*)&qc[nt*64 + d0];
        fv4 pv = pe[nt] + bp2q;
        fv4 yv = qv - kg + pv;
        fv4 vv = vg + pv;
        u16 yp[4], vp[4];
        #pragma unroll
        for (int r = 0; r < 4; ++r) { yp[r] = f2bf(yv[r]); vp[r] = f2bf(vv[r]); }
        *(bfv4*)&ylds[s*72 + d0] = *(const bfv4*)yp;
        *(bfv4*)&vt[s*72 + d0]   = *(const bfv4*)vp;
      }
    }
    __syncthreads();
    #pragma unroll
    for (int nt = 0; nt < 4; ++nt) {
      int s = nt*16 + ln;
      bfv8 b0 = *(const bfv8*)&ylds[s*72 + lq*8];
      bfv8 b1 = *(const bfv8*)&ylds[s*72 + 32 + lq*8];
      #pragma unroll
      for (int mt = 0; mt < 4; ++mt) {
        fv4 acc = {0.f,0.f,0.f,0.f};
        acc = MFMA16(A1[mt][0], b0, acc, 0, 0, 0);
        acc = MFMA16(A1[mt][1], b1, acc, 0, 0, 0);
        int h0 = 64*w + mt*16 + lq*4;
        fv4 bq = *(const fv4*)&sba1[h0];
        u16 hv[4];
        #pragma unroll
        for (int r = 0; r < 4; ++r) hv[r] = f2bf(fmaxf(acc[r] + bq[r], 0.f));
        *(bfv4*)&ha[s*264 + h0] = *(const bfv4*)hv;
      }
    }
    __syncthreads();
    {
      fv4 acc2[4];
      #pragma unroll
      for (int nt = 0; nt < 4; ++nt) acc2[nt] = (fv4){0.f,0.f,0.f,0.f};
      #pragma unroll
      for (int kk = 0; kk < 8; ++kk) {
        #pragma unroll
        for (int nt = 0; nt < 4; ++nt) {
          bfv8 bb = *(const bfv8*)&ha[(nt*16 + ln)*264 + kk*32 + lq*8];
          acc2[nt] = MFMA16(A2[kk], bb, acc2[nt], 0, 0, 0);
        }
      }
      fv4 ba2q = *(const fv4*)&sba2[d0];
      #pragma unroll
      for (int nt = 0; nt < 4; ++nt) {
        int s = nt*16 + ln;
        fv4 o = acc2[nt] + ba2q;
        *(fv4*)&at[s*68 + d0] = o;
      }
    }
    __syncthreads();
    {
      int dd = t & 63, pt = t >> 6;
      float a[16];
      #pragma unroll
      for (int k = 0; k < 16; ++k) a[k] = at[(pt*16 + k)*68 + dd];
      float mx = a[0];
      #pragma unroll
      for (int k = 1; k < 16; ++k) mx = fmaxf(mx, a[k]);
      float sum = 0.f, num = 0.f;
      #pragma unroll
      for (int k = 0; k < 16; ++k) {
        float e = __expf(a[k] - mx);
        sum += e;
        num += e * bf2f(vt[(pt*16 + k)*72 + dd]);
      }
      aggbf[(p0 + pt)*64 + dd] = f2bf(num / sum);
    }
    __syncthreads();
  }
}

// ---------------------------------------------------------------------------
// epilogue via MFMA: out = We @ agg + be + fq.  32 points/block, grid 256.
// ---------------------------------------------------------------------------
__global__ __launch_bounds__(256) void k_epilogue(
    const u16* __restrict__ aggbf, const u16* __restrict__ Webf,
    const float* __restrict__ be, const float* __restrict__ fq, float* __restrict__ out) {
  int bid = blockIdx.x;          // 256
  int b = bid >> 6, p0 = (bid & 63) * 32;
  int t = threadIdx.x;
  int w = t >> 6, l = t & 63, lq = l >> 4, ln = l & 15;
  bfv8 A[2][2];
  #pragma unroll
  for (int mt = 0; mt < 2; ++mt)
    #pragma unroll
    for (int kk = 0; kk < 2; ++kk)
      A[mt][kk] = *(const bfv8*)(Webf + ((w*2 + mt)*16 + ln)*64 + kk*32 + lq*8);
  fv4 acc[2][2];
  #pragma unroll
  for (int mt = 0; mt < 2; ++mt)
    #pragma unroll
    for (int nt = 0; nt < 2; ++nt) acc[mt][nt] = (fv4){0.f,0.f,0.f,0.f};
  #pragma unroll
  for (int nt = 0; nt < 2; ++nt) {
    const u16* bp = aggbf + (b*NN + p0 + nt*16 + ln)*64;
    bfv8 b0 = *(const bfv8*)(bp + lq*8);
    bfv8 b1 = *(const bfv8*)(bp + 32 + lq*8);
    #pragma unroll
    for (int mt = 0; mt < 2; ++mt) {
      acc[mt][nt] = MFMA16(A[mt][0], b0, acc[mt][nt], 0, 0, 0);
      acc[mt][nt] = MFMA16(A[mt][1], b1, acc[mt][nt], 0, 0, 0);
    }
  }
  #pragma unroll
  for (int mt = 0; mt < 2; ++mt) {
    int c0 = (w*2 + mt)*16 + lq*4;
    fv4 bev = *(const fv4*)&be[c0];
    #pragma unroll
    for (int nt = 0; nt < 2; ++nt) {
      #pragma unroll
      for (int r = 0; r < 4; ++r) {
        int c = c0 + r;
        int o = (b*128 + c)*NN + p0 + nt*16 + ln;
        out[o] = acc[mt][nt][r] + bev[r] + fq[o];
      }
    }
  }
}

// ---------------------------------------------------------------------------
extern "C" void kernel_launch(void* const* d_in, const int* in_sizes, int n_in,
                              void* d_out, int out_size, void* d_ws, size_t ws_size,
                              hipStream_t stream) {
  (void)in_sizes; (void)n_in; (void)out_size; (void)ws_size;
  const float* pq  = (const float*)d_in[0];
  const float* fq  = (const float*)d_in[1];
  const float* ps  = (const float*)d_in[2];
  const float* fs  = (const float*)d_in[3];
  const float* Wq  = (const float*)d_in[4];  const float* bq  = (const float*)d_in[5];
  const float* Wk  = (const float*)d_in[6];  const float* bk  = (const float*)d_in[7];
  const float* Wv  = (const float*)d_in[8];  const float* bv  = (const float*)d_in[9];
  const float* Wp1 = (const float*)d_in[10]; const float* bp1 = (const float*)d_in[11];
  const float* gp  = (const float*)d_in[12]; const float* btp = (const float*)d_in[13];
  const float* Wp2 = (const float*)d_in[14]; const float* bp2 = (const float*)d_in[15];
  const float* Wa1 = (const float*)d_in[16]; const float* ba1 = (const float*)d_in[17];
  const float* ga  = (const float*)d_in[18]; const float* bta = (const float*)d_in[19];
  const float* Wa2 = (const float*)d_in[20]; const float* ba2 = (const float*)d_in[21];
  const float* We  = (const float*)d_in[22]; const float* be  = (const float*)d_in[23];
  float* ws = (float*)d_ws;
  float* qT    = ws;                         // 524288
  float* kT    = ws + 524288;                // 524288
  float* vT    = ws + 1048576;               // 524288
  u16*   aggbf = (u16*)(ws + 1572864);       // 131072 fl region
  int*   idxb  = (int*)(ws + 2097152);       // 131072
  u16*   Wqbf  = (u16*)(ws + 2228224);       // 4096 fl
  u16*   Wkbf  = (u16*)(ws + 2232320);
  u16*   Wvbf  = (u16*)(ws + 2236416);
  u16*   Webf  = (u16*)(ws + 2240512);
  fv4*   psP   = (fv4*)(ws + 2244608);       // 131072 fl
  float* Wp1f  = ws + 2375680;               // 192
  float* bp1f  = ws + 2375872;               // 64
  float* ba1f  = ws + 2375936;               // 256
  float* G     = ws + 2376192;               // 4096
  float* ySum  = ws + 2380288;               // 64
  float* ySumP = ws + 2380352;               // 16384
  u16*   Wp2bf  = (u16*)(ws + 2396736);      // 2048 fl
  u16*   Wa2bf  = (u16*)(ws + 2398784);      // 8192 fl
  u16*   Wa1fbf = (u16*)(ws + 2406976);      // 8192 fl
  // d_out (4 MB) as staged scratch: xq/xs bf16 (consumed by k_qkv), then
  // posPart, then Gpart, finally the real output. All sequential on stream.
  u16*   xqbf    = (u16*)d_out;              // 2 MB
  u16*   xsbf    = xqbf + 1048576;           // 2 MB
  float* posPart = (float*)d_out;
  float* Gpart   = (float*)d_out;
  float* out     = (float*)d_out;

  k_prep<<<64, 256, 0, stream>>>(Wq, Wk, Wv, Wp2, Wa2, We, ps,
                                 Wqbf, Wkbf, Wvbf, Wp2bf, Wa2bf, Webf, psP);
  k_pack<<<256, 256, 0, stream>>>(fq, fs, xqbf, xsbf);
  k_qkv<<<256, 256, 0, stream>>>(xqbf, xsbf, Wqbf, Wkbf, Wvbf, bq, bk, bv, qT, kT, vT);
  k_knn<<<4096, 128, 0, stream>>>(pq, psP, idxb);
  k_posstats<<<512, 256, 0, stream>>>(pq, ps, idxb, posPart);
  k_posfinal<<<1, 256, 0, stream>>>(Wp1, bp1, gp, btp, posPart, Wp1f, bp1f);
  k_ystats<<<256, 256, 0, stream>>>(pq, ps, qT, kT, idxb, Wp1f, bp1f, Wp2bf, bp2,
                                    Gpart, ySumP);
  k_gred<<<17, 256, 0, stream>>>(Gpart, ySumP, G, ySum);
  k_attnfinal<<<256, 256, 0, stream>>>(Wa1, ba1, ga, bta, ySum, G, Wa1fbf, ba1f);
  k_main<<<1024, 256, 0, stream>>>(pq, ps, qT, kT, vT, idxb, Wp1f, bp1f, Wp2bf, bp2,
                                   Wa1fbf, ba1f, Wa2bf, ba2, aggbf);
  k_epilogue<<<256, 256, 0, stream>>>(aggbf, Webf, be, fq, out);
}